// Round 12
// baseline (216.944 us; speedup 1.0000x reference)
//
#include <hip/hip_runtime.h>
#include <hip/hip_bf16.h>

typedef short short8 __attribute__((ext_vector_type(8)));
typedef float floatx4 __attribute__((ext_vector_type(4)));
typedef int intx4 __attribute__((ext_vector_type(4)));
typedef int intx2 __attribute__((ext_vector_type(2)));

#define S_LEN 2048
#define DMODEL 1024
#define NH 16
#define HD 64
#define BATCH 2

static __device__ __forceinline__ short f2bf(float x) {
    __hip_bfloat16 h = __float2bfloat16(x);
    return *(short*)&h;
}

static __device__ __forceinline__ unsigned pk2(float lo, float hi) {
    // packed bf16 pair; compiler fuses to v_cvt_pk_bf16_f32 (m240: don't hand-asm)
    unsigned a = (unsigned)(unsigned short)f2bf(lo);
    unsigned b = (unsigned)(unsigned short)f2bf(hi);
    return a | (b << 16);
}

// async 16B global->LDS (wave-uniform LDS base + lane*16 contract)
static __device__ __forceinline__ void async_ld16(const __hip_bfloat16* g, __hip_bfloat16* l) {
    __builtin_amdgcn_global_load_lds(
        (const __attribute__((address_space(1))) unsigned int*)g,
        (__attribute__((address_space(3))) unsigned int*)l, 16, 0, 0);
}

// ---------------- fused prep: cvt (0..2047) + Wqkv transpose (2048..5119) + Wproj transpose (5120..6143) ----------------
__global__ __launch_bounds__(256) void prep_kernel(const float* __restrict__ X,
                                                   __hip_bfloat16* __restrict__ Y,
                                                   const float* __restrict__ W,
                                                   __hip_bfloat16* __restrict__ Wt,
                                                   const float* __restrict__ Wp,
                                                   __hip_bfloat16* __restrict__ Wpt) {
    const int bid = blockIdx.x;
    const int t = threadIdx.x;
    if (bid < 2048) {
        // cvt: hidden fp32 -> bf16, 2048 floats per block
        int i = (bid * 256 + t) * 8;
        floatx4 f0 = *(const floatx4*)&X[i];
        floatx4 f1 = *(const floatx4*)&X[i + 4];
        short8 s;
        s[0] = f2bf(f0[0]); s[1] = f2bf(f0[1]); s[2] = f2bf(f0[2]); s[3] = f2bf(f0[3]);
        s[4] = f2bf(f1[0]); s[5] = f2bf(f1[1]); s[6] = f2bf(f1[2]); s[7] = f2bf(f1[3]);
        *(short8*)&Y[i] = s;
    } else if (bid < 5120) {
        // Wqkv transpose+downcast: Wt[N=3072][K=1024] = bf16(W[K][N])
        __shared__ float tile[32][33];
        const int tid = bid - 2048;              // 0..3071
        const int n0 = (tid % 96) * 32, k0 = (tid / 96) * 32;
        const int tx = t & 31, ty = t >> 5;      // (32,8)
        const int K = 1024, N = 3072;
#pragma unroll
        for (int i = 0; i < 32; i += 8)
            tile[ty + i][tx] = W[(size_t)(k0 + ty + i) * N + n0 + tx];
        __syncthreads();
#pragma unroll
        for (int i = 0; i < 32; i += 8)
            Wt[(size_t)(n0 + ty + i) * K + k0 + tx] = __float2bfloat16(tile[tx][ty + i]);
    } else {
        // Wproj transpose+downcast: Wpt[N=1024][K=1024] = bf16(Wp[K][N])
        __shared__ float tile[32][33];
        const int tid = bid - 5120;              // 0..1023
        const int n0 = (tid & 31) * 32, k0 = (tid >> 5) * 32;
        const int tx = t & 31, ty = t >> 5;      // (32,8)
        const int K = 1024, N = 1024;
#pragma unroll
        for (int i = 0; i < 32; i += 8)
            tile[ty + i][tx] = Wp[(size_t)(k0 + ty + i) * N + n0 + tx];
        __syncthreads();
#pragma unroll
        for (int i = 0; i < 32; i += 8)
            Wpt[(size_t)(n0 + ty + i) * K + k0 + tx] = __float2bfloat16(tile[tx][ty + i]);
    }
}

// ---------------- MFMA GEMM 64x64 v3: fine-grid GEMM for BOTH projections ----------------
// r11 counters: the 128-tile QKV gemm was latency-bound with EVERYTHING idle
// (Mfma 13%, VALU 10%, HBM 12-16%, Occupancy 14.5%; grid 768 = 3 blocks/CU fixed).
// 64x64 tiles -> QKV grid (48,64) = 3072 blocks -> up to 8 blocks/CU = 32 waves/CU
// (LDS 16KB, VGPR ~60): 2.7x wave concurrency to hide the per-iter staging latency.
// mode 0: fp32 C out (proj). mode 1: QKV scatter epilogue; 64-wide tiles never
// straddle Q/K/V (1024) or head (64) boundaries. V quarter transposed via As (8KB).
__global__ __launch_bounds__(256) void gemm64(
    const __hip_bfloat16* __restrict__ A, const __hip_bfloat16* __restrict__ Bt,
    const float* __restrict__ bias, float* __restrict__ Cf,
    __hip_bfloat16* __restrict__ Qp, __hip_bfloat16* __restrict__ Kp,
    __hip_bfloat16* __restrict__ Vt, int M, int N, int K, int mode) {
    __shared__ __align__(16) __hip_bfloat16 As[2][64 * 32];
    __shared__ __align__(16) __hip_bfloat16 Bs[2][64 * 32];
    const int gx = gridDim.x, gy = gridDim.y;
    const int flat = blockIdx.y * gx + blockIdx.x;
    const int cpx = (gx * gy) >> 3;
    const int id2 = (flat & 7) * cpx + (flat >> 3);
    const int m0 = (id2 % gy) * 64, n0 = (id2 / gy) * 64;
    const int t = threadIdx.x;
    const int wave = t >> 6, lane = t & 63;
    const int quad = lane >> 4, m16 = lane & 15;
    const int srow = lane >> 2, scol = (lane & 3) * 8;

    // staging: wave w stages A rows [w*16,+16) and B rows [w*16,+16) (1 KB each)
    const int rb = wave * 16;
    const size_t aoff = (size_t)(m0 + rb + srow) * K + scol;
    const size_t boff = (size_t)(n0 + rb + srow) * K + scol;

    async_ld16(&A[aoff], &As[0][rb * 32]);
    async_ld16(&Bt[boff], &Bs[0][rb * 32]);
    __syncthreads();

    floatx4 acc[4] = {};
    const int NI = K >> 5;
    for (int it = 0; it < NI; ++it) {
        const int cur = it & 1;
        if (it < NI - 1) {
            const int k0 = (it + 1) * 32;
            async_ld16(&A[aoff + k0], &As[cur ^ 1][rb * 32]);
            async_ld16(&Bt[boff + k0], &Bs[cur ^ 1][rb * 32]);
        }
        short8 af[4];
#pragma unroll
        for (int i = 0; i < 4; i++)
            af[i] = *(const short8*)&As[cur][(i * 16 + m16) * 32 + quad * 8];
        short8 bfr = *(const short8*)&Bs[cur][(wave * 16 + m16) * 32 + quad * 8];
#pragma unroll
        for (int i = 0; i < 4; i++)
            acc[i] = __builtin_amdgcn_mfma_f32_16x16x32_bf16(af[i], bfr, acc[i], 0, 0, 0);
        __syncthreads();
    }

    const int col = n0 + wave * 16 + m16;
    const float bv = bias[col];
    if (mode == 0) {
#pragma unroll
        for (int i = 0; i < 4; i++)
#pragma unroll
            for (int r = 0; r < 4; r++) {
                int row = m0 + i * 16 + quad * 4 + r;
                Cf[(size_t)row * N + col] = acc[i][r] + bv;
            }
    } else if (n0 < 2 * DMODEL) {
        // Q/K scatter: tt/h uniform per tile (n0 % 64 == 0); d = wave*16+m16
        const int tt = col >> 10, rem = col & 1023;
        const int h = rem >> 6, d = rem & 63;
        __hip_bfloat16* dstp = tt == 0 ? Qp : Kp;
#pragma unroll
        for (int i = 0; i < 4; i++)
#pragma unroll
            for (int r = 0; r < 4; r++) {
                int row = m0 + i * 16 + quad * 4 + r;
                int b = row >> 11, s = row & 2047;
                dstp[((size_t)(b * NH + h) * S_LEN + s) * HD + d] = __float2bfloat16(acc[i][r] + bv);
            }
    } else {
        // V region: transpose the 64d x 64s quarter via As (8 KB exact), then
        // coalesced 32B Vt row-segments.
        char* T = (char*)As;
        const int d_loc = wave * 16 + m16;          // 0..63
#pragma unroll
        for (int i = 0; i < 4; i++) {
            intx2 v;
            v[0] = (int)pk2(acc[i][0] + bv, acc[i][1] + bv);
            v[1] = (int)pk2(acc[i][2] + bv, acc[i][3] + bv);
            *(intx2*)(T + d_loc * 128 + (i * 16 + quad * 4) * 2) = v;
        }
        __syncthreads();
        {
            const int dl = t >> 2;                  // 0..63
            const int sseg = (t & 3) * 16;          // 0,16,32,48
            short8 a0 = *(const short8*)(T + dl * 128 + sseg * 2);
            short8 a1 = *(const short8*)(T + dl * 128 + sseg * 2 + 16);
            const int hh = (n0 - 2 * DMODEL) >> 6;
            const int bq = m0 >> 11, s_base = m0 & 2047;
            __hip_bfloat16* dst = &Vt[((size_t)(bq * NH + hh) * HD + dl) * S_LEN + s_base + sseg];
            *(short8*)dst = a0;
            *(short8*)(dst + 8) = a1;
        }
    }
}

// ---------------- MFMA flash attention v9 (r8-exact, verified 57.3 us): split-K, 8 waves ----------------
__global__ __launch_bounds__(512, 8) void attn_kernel(
    const __hip_bfloat16* __restrict__ Q,   // [B,H,S,HD]
    const __hip_bfloat16* __restrict__ K,   // [B,H,S,HD]
    const __hip_bfloat16* __restrict__ Vt,  // [B,H,HD,S]
    const float* __restrict__ mask,         // [B,S] additive fp32
    __hip_bfloat16* __restrict__ ctx) {     // [B,S,D]
    __shared__ __align__(16) __hip_bfloat16 smem[16384];  // 32 KB K/V dbuf + merge
    __shared__ float wsm[S_LEN];                          // 8 KB mask table
    const int bh = blockIdx.x;
    const int b = bh >> 4, h = bh & 15;
    const int t = threadIdx.x, wave = t >> 6, lane = t & 63;
    const int team = wave >> 2, tw = wave & 3;
    const int quad = lane >> 4, m16 = lane & 15;
    const int qbase = blockIdx.y * 64 + tw * 16;
    const int ko = team * (S_LEN / 2);      // this team's key offset
    const __hip_bfloat16* Qh = Q + (size_t)bh * S_LEN * HD;
    const __hip_bfloat16* Kh = K + (size_t)bh * S_LEN * HD;
    const __hip_bfloat16* Vh = Vt + (size_t)bh * HD * S_LEN;
    const float* mb = mask + (size_t)b * S_LEN;
    const float LOG2E = 1.44269504f;
    const float scale2 = 0.125f * LOG2E;    // softmax scale pre-folded with log2(e)
    const float M_FIX2 = 20.0f * LOG2E;     // fixed-max bias (cancels in o/li)

    __hip_bfloat16* Ksb = smem + team * 8192;          // 2 bufs x 2048 elems
    __hip_bfloat16* Vsb = smem + team * 8192 + 4096;   // 2 bufs x 2048 elems

    // mask table: w[s] = mask[s]*log2e - M_FIX2
    {
        floatx4 mv = *(const floatx4*)&mb[t * 4];
        floatx4 wv;
#pragma unroll
        for (int r = 0; r < 4; r++) wv[r] = __builtin_fmaf(mv[r], LOG2E, -M_FIX2);
        *(floatx4*)&wsm[t * 4] = wv;
    }

    // DMA source offsets (per-lane, swizzled) and LDS dsts.
    const int kr = lane >> 3, kc = lane & 7;
    const int kgoff = (tw * 8 + kr) * HD + ((kc ^ kr) * 8);
    const int vr = lane >> 2, vc = lane & 3;
    const int vd = tw * 16 + vr;
    const int vgoff = vd * S_LEN + (((vc ^ ((vd >> 1) & 3))) * 8);
    __hip_bfloat16* kdst0 = Ksb + tw * 512;
    __hip_bfloat16* kdst1 = Ksb + 2048 + tw * 512;
    __hip_bfloat16* vdst0 = Vsb + tw * 512;
    __hip_bfloat16* vdst1 = Vsb + 2048 + tw * 512;

    // Q fragments (B-operand: lane m16 <-> query m16, chunk quad <-> hd)
    short8 aq0 = *(const short8*)&Qh[(size_t)(qbase + m16) * HD + quad * 8];
    short8 aq1 = *(const short8*)&Qh[(size_t)(qbase + m16) * HD + 32 + quad * 8];

    const short ONEB = (short)0x3F80;  // bf16 1.0
    const short8 ones = {ONEB, ONEB, ONEB, ONEB, ONEB, ONEB, ONEB, ONEB};

    // prologue: DMA tile 0 into buffer 0
    async_ld16(&Kh[(size_t)ko * HD + kgoff], kdst0);
    async_ld16(&Vh[(size_t)ko + vgoff], vdst0);
    __syncthreads();

    floatx4 o[4] = {};
    floatx4 lacc = {};
    const int swk = m16 & 7;                          // K fragment-read swizzle key
    const int e = quad & 1;                           // exchange parity
    const int C = ((quad & 1) << 1) | (quad >> 1);    // owned 8-key chunk (0,2,1,3)
    const int vsl = (C ^ ((m16 >> 1) & 3)) * 8;       // V-slot offset (g(d)=(m16>>1)&3)

    const int NIT = (S_LEN / 2) / 32;  // 32 iterations of 32 keys per team
    for (int it = 0; it < NIT; it++) {
        const int k0 = it * 32;
        const int cur = it & 1;
        // issue DMA for next tile into the other buffer (overlaps this iter's compute)
        if (it < NIT - 1) {
            async_ld16(&Kh[(size_t)(ko + k0 + 32) * HD + kgoff], cur ? kdst0 : kdst1);
            async_ld16(&Vh[(size_t)(ko + k0 + 32) + vgoff], cur ? vdst0 : vdst1);
        }

        // ---- QK^T (swapped): sc[kt][r] = S[key = 16kt+4quad+r][q = m16] ----
        const __hip_bfloat16* Kc = Ksb + cur * 2048;
        floatx4 sc[2] = {};
        __builtin_amdgcn_s_setprio(1);
#pragma unroll
        for (int kt = 0; kt < 2; kt++) {
            const int row = kt * 16 + m16;
            short8 ak0 = *(const short8*)&Kc[row * 64 + ((quad ^ swk) * 8)];
            short8 ak1 = *(const short8*)&Kc[row * 64 + (((quad + 4) ^ swk) * 8)];
            sc[kt] = __builtin_amdgcn_mfma_f32_16x16x32_bf16(ak0, aq0, sc[kt], 0, 0, 0);
            sc[kt] = __builtin_amdgcn_mfma_f32_16x16x32_bf16(ak1, aq1, sc[kt], 0, 0, 0);
        }
        __builtin_amdgcn_s_setprio(0);

        // ---- softmax numerator (in-register) + pack to bf16 dword pairs ----
        unsigned dk[2][2];
#pragma unroll
        for (int kt = 0; kt < 2; kt++) {
            floatx4 wv = *(const floatx4*)&wsm[ko + k0 + kt * 16 + quad * 4];
            float p0 = __builtin_amdgcn_exp2f(__builtin_fmaf(sc[kt][0], scale2, wv[0]));
            float p1 = __builtin_amdgcn_exp2f(__builtin_fmaf(sc[kt][1], scale2, wv[1]));
            float p2 = __builtin_amdgcn_exp2f(__builtin_fmaf(sc[kt][2], scale2, wv[2]));
            float p3 = __builtin_amdgcn_exp2f(__builtin_fmaf(sc[kt][3], scale2, wv[3]));
            dk[kt][0] = pk2(p0, p1);
            dk[kt][1] = pk2(p2, p3);
        }

        // ---- chunk exchange with lane^16 (quad^1): assemble chunk C(quad) ----
        unsigned s0 = e ? dk[0][0] : dk[1][0];
        unsigned s1 = e ? dk[0][1] : dk[1][1];
        unsigned r0 = (unsigned)__builtin_amdgcn_ds_swizzle((int)s0, 0x401F);
        unsigned r1 = (unsigned)__builtin_amdgcn_ds_swizzle((int)s1, 0x401F);
        intx4 wa;
        wa[0] = (int)(e ? r0 : dk[0][0]);   // keys 8C+0,1
        wa[1] = (int)(e ? r1 : dk[0][1]);   // keys 8C+2,3
        wa[2] = (int)(e ? dk[1][0] : r0);   // keys 8C+4,5
        wa[3] = (int)(e ? dk[1][1] : r1);   // keys 8C+6,7
        short8 ap = *(short8*)&wa;

        // ---- PV + row-sum (ones); V-side reads the SAME chunk C(quad) ----
        const __hip_bfloat16* Vc = Vsb + cur * 2048;
        __builtin_amdgcn_s_setprio(1);
        lacc = __builtin_amdgcn_mfma_f32_16x16x32_bf16(ap, ones, lacc, 0, 0, 0);
#pragma unroll
        for (int tt = 0; tt < 4; tt++) {
            const int d = tt * 16 + m16;
            short8 bv = *(const short8*)&Vc[d * 32 + vsl];
            o[tt] = __builtin_amdgcn_mfma_f32_16x16x32_bf16(ap, bv, o[tt], 0, 0, 0);
        }
        __builtin_amdgcn_s_setprio(0);
        __syncthreads();  // drains DMA (vmcnt) + barrier: next buffer ready, cur reusable
    }

    // ---- merge the two key-halves (fixed-max => partials are additive) ----
    float* xch = (float*)smem;
    const int xi = (tw * 64 + lane) * 21;
    if (team == 1) {
#pragma unroll
        for (int tt = 0; tt < 4; tt++)
#pragma unroll
            for (int r = 0; r < 4; r++) xch[xi + tt * 4 + r] = o[tt][r];
#pragma unroll
        for (int r = 0; r < 4; r++) xch[xi + 16 + r] = lacc[r];
    }
    __syncthreads();
    if (team == 0) {
        float li[4];
#pragma unroll
        for (int r = 0; r < 4; r++) li[r] = 1.0f / (lacc[r] + xch[xi + 16 + r]);
#pragma unroll
        for (int tt = 0; tt < 4; tt++)
#pragma unroll
            for (int r = 0; r < 4; r++) {
                int srow = qbase + quad * 4 + r;
                int d = tt * 16 + m16;
                float v = (o[tt][r] + xch[xi + tt * 4 + r]) * li[r];
                ctx[((size_t)b * S_LEN + srow) * DMODEL + h * HD + d] = __float2bfloat16(v);
            }
    }
}

extern "C" void kernel_launch(void* const* d_in, const int* in_sizes, int n_in,
                              void* d_out, int out_size, void* d_ws, size_t ws_size,
                              hipStream_t stream) {
    (void)in_sizes; (void)n_in; (void)out_size; (void)ws_size;
    const float* hidden = (const float*)d_in[0];  // [2,2048,1024] fp32
    const float* mask   = (const float*)d_in[1];  // [2,1,1,2048] fp32
    const float* Wqkv   = (const float*)d_in[2];  // [1024,3072] fp32 [in,out]
    const float* bqkv   = (const float*)d_in[3];  // [3072] fp32
    const float* Wproj  = (const float*)d_in[4];  // [1024,1024] fp32 [in,out]
    const float* bproj  = (const float*)d_in[5];  // [1024] fp32
    float* out = (float*)d_out;                   // fp32 output

    // ---- workspace layout ----
    __hip_bfloat16* ws = (__hip_bfloat16*)d_ws;
    const size_t Q4 = 4u * 1024 * 1024;
    __hip_bfloat16* Qp      = ws;
    __hip_bfloat16* Kp      = ws + 1 * Q4;
    __hip_bfloat16* Vt      = ws + 2 * Q4;
    __hip_bfloat16* hid_bf  = ws + 3 * Q4;
    __hip_bfloat16* ctx     = ws + 3 * Q4;                    // overlaps hid_bf (disjoint lifetime)
    __hip_bfloat16* Wqkv_t  = ws + 4 * Q4;                    // 3M elems
    __hip_bfloat16* Wproj_t = ws + 4 * Q4 + 3u * 1024 * 1024; // 1M elems (no alias)

    // prep: cvt (2048) + Wqkv transpose (3072) + Wproj transpose (1024)
    prep_kernel<<<dim3(6144), 256, 0, stream>>>(hidden, hid_bf, Wqkv, Wqkv_t, Wproj, Wproj_t);

    // QKV projection + scatter: M=4096, N=3072, K=1024, 64x64 tiles (3072 blocks)
    gemm64<<<dim3(3072 / 64, 4096 / 64), 256, 0, stream>>>(
        hid_bf, Wqkv_t, bqkv, nullptr, Qp, Kp, Vt, BATCH * S_LEN, 3 * DMODEL, DMODEL, 1);

    // attn (pure, verified 57.3us config)
    attn_kernel<<<dim3(BATCH * NH, S_LEN / 64), 512, 0, stream>>>(Qp, Kp, Vt, mask, ctx);

    // output projection: M=4096, N=1024, K=1024 -> fp32 out, 64x64 tiles (1024 blocks)
    gemm64<<<dim3(1024 / 64, 4096 / 64), 256, 0, stream>>>(
        ctx, Wproj_t, bproj, out, nullptr, nullptr, nullptr, BATCH * S_LEN, DMODEL, DMODEL, 0);
}

// Round 14
// 214.281 us; speedup vs baseline: 1.0124x; 1.0124x over previous
//
#include <hip/hip_runtime.h>
#include <hip/hip_bf16.h>

typedef short short8 __attribute__((ext_vector_type(8)));
typedef float floatx4 __attribute__((ext_vector_type(4)));
typedef int intx4 __attribute__((ext_vector_type(4)));
typedef int intx2 __attribute__((ext_vector_type(2)));

#define S_LEN 2048
#define DMODEL 1024
#define NH 16
#define HD 64
#define BATCH 2

static __device__ __forceinline__ short f2bf(float x) {
    __hip_bfloat16 h = __float2bfloat16(x);
    return *(short*)&h;
}

static __device__ __forceinline__ unsigned pk2(float lo, float hi) {
    // packed bf16 pair; compiler fuses to v_cvt_pk_bf16_f32 (m240: don't hand-asm)
    unsigned a = (unsigned)(unsigned short)f2bf(lo);
    unsigned b = (unsigned)(unsigned short)f2bf(hi);
    return a | (b << 16);
}

// async 16B global->LDS (wave-uniform LDS base + lane*16 contract)
static __device__ __forceinline__ void async_ld16(const __hip_bfloat16* g, __hip_bfloat16* l) {
    __builtin_amdgcn_global_load_lds(
        (const __attribute__((address_space(1))) unsigned int*)g,
        (__attribute__((address_space(3))) unsigned int*)l, 16, 0, 0);
}

// ---------------- fused prep: cvt (0..2047) + Wqkv transpose (2048..5119) + Wproj transpose (5120..6143) ----------------
__global__ __launch_bounds__(256) void prep_kernel(const float* __restrict__ X,
                                                   __hip_bfloat16* __restrict__ Y,
                                                   const float* __restrict__ W,
                                                   __hip_bfloat16* __restrict__ Wt,
                                                   const float* __restrict__ Wp,
                                                   __hip_bfloat16* __restrict__ Wpt) {
    const int bid = blockIdx.x;
    const int t = threadIdx.x;
    if (bid < 2048) {
        // cvt: hidden fp32 -> bf16, 2048 floats per block
        int i = (bid * 256 + t) * 8;
        floatx4 f0 = *(const floatx4*)&X[i];
        floatx4 f1 = *(const floatx4*)&X[i + 4];
        short8 s;
        s[0] = f2bf(f0[0]); s[1] = f2bf(f0[1]); s[2] = f2bf(f0[2]); s[3] = f2bf(f0[3]);
        s[4] = f2bf(f1[0]); s[5] = f2bf(f1[1]); s[6] = f2bf(f1[2]); s[7] = f2bf(f1[3]);
        *(short8*)&Y[i] = s;
    } else if (bid < 5120) {
        // Wqkv transpose+downcast: Wt[N=3072][K=1024] = bf16(W[K][N])
        __shared__ float tile[32][33];
        const int tid = bid - 2048;              // 0..3071
        const int n0 = (tid % 96) * 32, k0 = (tid / 96) * 32;
        const int tx = t & 31, ty = t >> 5;      // (32,8)
        const int K = 1024, N = 3072;
#pragma unroll
        for (int i = 0; i < 32; i += 8)
            tile[ty + i][tx] = W[(size_t)(k0 + ty + i) * N + n0 + tx];
        __syncthreads();
#pragma unroll
        for (int i = 0; i < 32; i += 8)
            Wt[(size_t)(n0 + ty + i) * K + k0 + tx] = __float2bfloat16(tile[tx][ty + i]);
    } else {
        // Wproj transpose+downcast: Wpt[N=1024][K=1024] = bf16(Wp[K][N])
        __shared__ float tile[32][33];
        const int tid = bid - 5120;              // 0..1023
        const int n0 = (tid & 31) * 32, k0 = (tid >> 5) * 32;
        const int tx = t & 31, ty = t >> 5;      // (32,8)
        const int K = 1024, N = 1024;
#pragma unroll
        for (int i = 0; i < 32; i += 8)
            tile[ty + i][tx] = Wp[(size_t)(k0 + ty + i) * N + n0 + tx];
        __syncthreads();
#pragma unroll
        for (int i = 0; i < 32; i += 8)
            Wpt[(size_t)(n0 + ty + i) * K + k0 + tx] = __float2bfloat16(tile[tx][ty + i]);
    }
}

// ---------------- MFMA GEMM v4 (r11-exact): 128x128, BK=32, dbuf prefetch ----------------
__global__ __launch_bounds__(256) void gemm128(
    const __hip_bfloat16* __restrict__ A, const __hip_bfloat16* __restrict__ Bt,
    const float* __restrict__ bias, float* __restrict__ Cf,
    __hip_bfloat16* __restrict__ Qp, __hip_bfloat16* __restrict__ Kp,
    __hip_bfloat16* __restrict__ Vt, int M, int N, int K, int mode) {
    __shared__ __align__(16) __hip_bfloat16 As[2][128 * 32];
    __shared__ __align__(16) __hip_bfloat16 Bs[2][128 * 32];
    // XCD-chunked block swizzle (hardware round-robins flat id across 8 XCDs)
    const int gx = gridDim.x, gy = gridDim.y;
    const int flat = blockIdx.y * gx + blockIdx.x;
    const int cpx = (gx * gy) >> 3;
    const int id2 = (flat & 7) * cpx + (flat >> 3);
    const int m0 = (id2 % gy) * 128, n0 = (id2 / gy) * 128;
    const int t = threadIdx.x;
    const int wave = t >> 6, lane = t & 63;
    const int quad = lane >> 4, m16 = lane & 15;
    const int wm = (wave >> 1) * 64, wn = (wave & 1) * 64;
    const int srow = lane >> 2, scol = (lane & 3) * 8;

    const int rb0 = wave * 32, rb1 = wave * 32 + 16;
    const size_t aoff0 = (size_t)(m0 + rb0 + srow) * K + scol;
    const size_t aoff1 = (size_t)(m0 + rb1 + srow) * K + scol;
    const size_t boff0 = (size_t)(n0 + rb0 + srow) * K + scol;
    const size_t boff1 = (size_t)(n0 + rb1 + srow) * K + scol;

    // prologue: stage K-tile 0 into buffer 0
    async_ld16(&A[aoff0], &As[0][rb0 * 32]);
    async_ld16(&A[aoff1], &As[0][rb1 * 32]);
    async_ld16(&Bt[boff0], &Bs[0][rb0 * 32]);
    async_ld16(&Bt[boff1], &Bs[0][rb1 * 32]);
    __syncthreads();

    floatx4 acc[4][4] = {};
    const int NI = K >> 5;
    for (int it = 0; it < NI; ++it) {
        const int cur = it & 1;
        if (it < NI - 1) {
            const int k0 = (it + 1) * 32;
            async_ld16(&A[aoff0 + k0], &As[cur ^ 1][rb0 * 32]);
            async_ld16(&A[aoff1 + k0], &As[cur ^ 1][rb1 * 32]);
            async_ld16(&Bt[boff0 + k0], &Bs[cur ^ 1][rb0 * 32]);
            async_ld16(&Bt[boff1 + k0], &Bs[cur ^ 1][rb1 * 32]);
        }
        short8 af[4], bfr[4];
#pragma unroll
        for (int i = 0; i < 4; i++)
            af[i] = *(const short8*)&As[cur][(wm + i * 16 + m16) * 32 + quad * 8];
#pragma unroll
        for (int j = 0; j < 4; j++)
            bfr[j] = *(const short8*)&Bs[cur][(wn + j * 16 + m16) * 32 + quad * 8];
#pragma unroll
        for (int i = 0; i < 4; i++)
#pragma unroll
            for (int j = 0; j < 4; j++)
                acc[i][j] = __builtin_amdgcn_mfma_f32_16x16x32_bf16(af[i], bfr[j], acc[i][j], 0, 0, 0);
        __syncthreads();  // drains prefetch DMA + barrier: next buffer ready, cur reusable
    }
    if (mode == 0) {
#pragma unroll
        for (int i = 0; i < 4; i++)
#pragma unroll
            for (int j = 0; j < 4; j++) {
                int col = n0 + wn + j * 16 + m16;
                float bv = bias[col];
#pragma unroll
                for (int r = 0; r < 4; r++) {
                    int row = m0 + wm + i * 16 + quad * 4 + r;
                    Cf[(size_t)row * N + col] = acc[i][j][r] + bv;
                }
            }
    } else if (n0 < 2 * DMODEL) {
        // Q/K scatter (32B-granule)
#pragma unroll
        for (int i = 0; i < 4; i++)
#pragma unroll
            for (int j = 0; j < 4; j++) {
                int col = n0 + wn + j * 16 + m16;
                float bv = bias[col];
#pragma unroll
                for (int r = 0; r < 4; r++) {
                    int row = m0 + wm + i * 16 + quad * 4 + r;
                    __hip_bfloat16 hv = __float2bfloat16(acc[i][j][r] + bv);
                    int tt = col >> 10, rem = col & 1023;
                    int h = rem >> 6, d = rem & 63;
                    int b = row >> 11, s = row & 2047;
                    if (tt == 0) Qp[((size_t)(b * NH + h) * S_LEN + s) * HD + d] = hv;
                    else         Kp[((size_t)(b * NH + h) * S_LEN + s) * HD + d] = hv;
                }
            }
    } else {
        // V region: per-wave LDS transpose then coalesced Vt rows.
        char* T = (char*)As;
        const int bq = m0 >> 11;         // batch (tiles never straddle: 2048%128==0)
        const int s_base = m0 & 2047;
        for (int p = 0; p < 4; p++) {
            if (wave == p) {
#pragma unroll
                for (int j = 0; j < 4; j++) {
                    const int drow = j * 16 + m16;              // d_loc = col quarter-local
                    const float bv = bias[n0 + wn + j * 16 + m16];
                    const int within = (quad & 1) * 4;          // s_loc&7 base
#pragma unroll
                    for (int i = 0; i < 4; i++) {
                        const int colc = i * 2 + (quad >> 1);   // logical s-chunk
                        const int physc = colc ^ (drow & 7);
                        intx2 v;
                        v[0] = (int)pk2(acc[i][j][0] + bv, acc[i][j][1] + bv);
                        v[1] = (int)pk2(acc[i][j][2] + bv, acc[i][j][3] + bv);
                        *(intx2*)(T + drow * 128 + physc * 16 + within * 2) = v;
                    }
                }
            }
            __syncthreads();
            {
                const int dl = t >> 2;              // 0..63
                const int sseg = (t & 3) * 16;      // 0,16,32,48
                const int c0 = (sseg >> 3) ^ (dl & 7);
                const int c1 = ((sseg >> 3) + 1) ^ (dl & 7);
                short8 a0 = *(const short8*)(T + dl * 128 + c0 * 16);
                short8 a1 = *(const short8*)(T + dl * 128 + c1 * 16);
                const int hh = (n0 - 2 * DMODEL + (p & 1) * 64) >> 6;
                const int sg = s_base + (p >> 1) * 64 + sseg;
                __hip_bfloat16* dst = &Vt[((size_t)(bq * NH + hh) * HD + dl) * S_LEN + sg];
                *(short8*)dst = a0;
                *(short8*)(dst + 8) = a1;
            }
            __syncthreads();
        }
    }
}

// ---------------- MFMA GEMM 64x64 (proj, r11-exact): dbuf, 4 blocks/CU ----------------
__global__ __launch_bounds__(256) void gemm64(
    const __hip_bfloat16* __restrict__ A, const __hip_bfloat16* __restrict__ Bt,
    const float* __restrict__ bias, float* __restrict__ Cf, int M, int N, int K) {
    __shared__ __align__(16) __hip_bfloat16 As[2][64 * 32];
    __shared__ __align__(16) __hip_bfloat16 Bs[2][64 * 32];
    const int gx = gridDim.x, gy = gridDim.y;
    const int flat = blockIdx.y * gx + blockIdx.x;
    const int cpx = (gx * gy) >> 3;
    const int id2 = (flat & 7) * cpx + (flat >> 3);
    const int m0 = (id2 % gy) * 64, n0 = (id2 / gy) * 64;
    const int t = threadIdx.x;
    const int wave = t >> 6, lane = t & 63;
    const int quad = lane >> 4, m16 = lane & 15;
    const int srow = lane >> 2, scol = (lane & 3) * 8;

    const int rb = wave * 16;
    const size_t aoff = (size_t)(m0 + rb + srow) * K + scol;
    const size_t boff = (size_t)(n0 + rb + srow) * K + scol;

    async_ld16(&A[aoff], &As[0][rb * 32]);
    async_ld16(&Bt[boff], &Bs[0][rb * 32]);
    __syncthreads();

    floatx4 acc[4] = {};
    const int NI = K >> 5;
    for (int it = 0; it < NI; ++it) {
        const int cur = it & 1;
        if (it < NI - 1) {
            const int k0 = (it + 1) * 32;
            async_ld16(&A[aoff + k0], &As[cur ^ 1][rb * 32]);
            async_ld16(&Bt[boff + k0], &Bs[cur ^ 1][rb * 32]);
        }
        short8 af[4];
#pragma unroll
        for (int i = 0; i < 4; i++)
            af[i] = *(const short8*)&As[cur][(i * 16 + m16) * 32 + quad * 8];
        short8 bfr = *(const short8*)&Bs[cur][(wave * 16 + m16) * 32 + quad * 8];
#pragma unroll
        for (int i = 0; i < 4; i++)
            acc[i] = __builtin_amdgcn_mfma_f32_16x16x32_bf16(af[i], bfr, acc[i], 0, 0, 0);
        __syncthreads();
    }
    {
        const int col = n0 + wave * 16 + m16;
        const float bv = bias[col];
#pragma unroll
        for (int i = 0; i < 4; i++)
#pragma unroll
            for (int r = 0; r < 4; r++) {
                int row = m0 + i * 16 + quad * 4 + r;
                Cf[(size_t)row * N + col] = acc[i][r] + bv;
            }
    }
}

// ---------------- MFMA flash attention v11: split-K + PV(t-1) ∥ QK(t) pipeline ----------------
// v11 vs v9 (T15-analog, m214v36 attn-proven +7-11%): v9's per-iter serial chain was
// ds_read K -> QK MFMA -> exp/pack/exchange -> ds_read V -> PV MFMA -> barrier; PV(t)
// depends on softmax(t) so nothing hides the VALU phase. Now ap is held one iteration
// and PV(t-1) executes during iter t: independent of QK(t)/softmax(t), so its 5 MFMAs
// + 5 ds_reads interleave into the softmax bubbles. V(t) DMA moves to iter t (drained
// by barrier t, consumed at t+1); Vb[t&1] held V(t-2), last read before barrier t-1 ->
// no overwrite hazard. Still 2xK + 2xV buffers, +4 VGPR (ap_prev).
__global__ __launch_bounds__(512, 8) void attn_kernel(
    const __hip_bfloat16* __restrict__ Q,   // [B,H,S,HD]
    const __hip_bfloat16* __restrict__ K,   // [B,H,S,HD]
    const __hip_bfloat16* __restrict__ Vt,  // [B,H,HD,S]
    const float* __restrict__ mask,         // [B,S] additive fp32
    __hip_bfloat16* __restrict__ ctx) {     // [B,S,D]
    __shared__ __align__(16) __hip_bfloat16 smem[16384];  // 32 KB K/V dbuf + merge
    __shared__ float wsm[S_LEN];                          // 8 KB mask table
    const int bh = blockIdx.x;
    const int b = bh >> 4, h = bh & 15;
    const int t = threadIdx.x, wave = t >> 6, lane = t & 63;
    const int team = wave >> 2, tw = wave & 3;
    const int quad = lane >> 4, m16 = lane & 15;
    const int qbase = blockIdx.y * 64 + tw * 16;
    const int ko = team * (S_LEN / 2);      // this team's key offset
    const __hip_bfloat16* Qh = Q + (size_t)bh * S_LEN * HD;
    const __hip_bfloat16* Kh = K + (size_t)bh * S_LEN * HD;
    const __hip_bfloat16* Vh = Vt + (size_t)bh * HD * S_LEN;
    const float* mb = mask + (size_t)b * S_LEN;
    const float LOG2E = 1.44269504f;
    const float scale2 = 0.125f * LOG2E;    // softmax scale pre-folded with log2(e)
    const float M_FIX2 = 20.0f * LOG2E;     // fixed-max bias (cancels in o/li)

    __hip_bfloat16* Ksb = smem + team * 8192;          // 2 bufs x 2048 elems
    __hip_bfloat16* Vsb = smem + team * 8192 + 4096;   // 2 bufs x 2048 elems

    // mask table: w[s] = mask[s]*log2e - M_FIX2
    {
        floatx4 mv = *(const floatx4*)&mb[t * 4];
        floatx4 wv;
#pragma unroll
        for (int r = 0; r < 4; r++) wv[r] = __builtin_fmaf(mv[r], LOG2E, -M_FIX2);
        *(floatx4*)&wsm[t * 4] = wv;
    }

    // DMA source offsets (per-lane, swizzled) and LDS dsts.
    const int kr = lane >> 3, kc = lane & 7;
    const int kgoff = (tw * 8 + kr) * HD + ((kc ^ kr) * 8);
    const int vr = lane >> 2, vc = lane & 3;
    const int vd = tw * 16 + vr;
    const int vgoff = vd * S_LEN + (((vc ^ ((vd >> 1) & 3))) * 8);
    __hip_bfloat16* kdst0 = Ksb + tw * 512;
    __hip_bfloat16* kdst1 = Ksb + 2048 + tw * 512;
    __hip_bfloat16* vdst0 = Vsb + tw * 512;
    __hip_bfloat16* vdst1 = Vsb + 2048 + tw * 512;

    // Q fragments (B-operand: lane m16 <-> query m16, chunk quad <-> hd)
    short8 aq0 = *(const short8*)&Qh[(size_t)(qbase + m16) * HD + quad * 8];
    short8 aq1 = *(const short8*)&Qh[(size_t)(qbase + m16) * HD + 32 + quad * 8];

    const short ONEB = (short)0x3F80;  // bf16 1.0
    const short8 ones = {ONEB, ONEB, ONEB, ONEB, ONEB, ONEB, ONEB, ONEB};

    // prologue: DMA K-tile 0 only (V(0) is issued at iter 0)
    async_ld16(&Kh[(size_t)ko * HD + kgoff], kdst0);
    __syncthreads();

    floatx4 o[4] = {};
    floatx4 lacc = {};
    short8 ap_prev;                                   // P fragment of tile t-1
    const int swk = m16 & 7;                          // K fragment-read swizzle key
    const int e = quad & 1;                           // exchange parity
    const int C = ((quad & 1) << 1) | (quad >> 1);    // owned 8-key chunk (0,2,1,3)
    const int vsl = (C ^ ((m16 >> 1) & 3)) * 8;       // V-slot offset (g(d)=(m16>>1)&3)

    const int NIT = (S_LEN / 2) / 32;  // 32 iterations of 32 keys per team
    for (int it = 0; it < NIT; it++) {
        const int k0 = it * 32;
        const int cur = it & 1;
        // DMA: K(t+1) into the other K buffer; V(t) into Vb[t&1] (used at t+1)
        if (it < NIT - 1)
            async_ld16(&Kh[(size_t)(ko + k0 + 32) * HD + kgoff], cur ? kdst0 : kdst1);
        async_ld16(&Vh[(size_t)(ko + k0) + vgoff], cur ? vdst1 : vdst0);

        // ---- QK^T (swapped): sc[kt][r] = S[key = 16kt+4quad+r][q = m16] ----
        const __hip_bfloat16* Kc = Ksb + cur * 2048;
        floatx4 sc[2] = {};
        __builtin_amdgcn_s_setprio(1);
#pragma unroll
        for (int kt = 0; kt < 2; kt++) {
            const int row = kt * 16 + m16;
            short8 ak0 = *(const short8*)&Kc[row * 64 + ((quad ^ swk) * 8)];
            short8 ak1 = *(const short8*)&Kc[row * 64 + (((quad + 4) ^ swk) * 8)];
            sc[kt] = __builtin_amdgcn_mfma_f32_16x16x32_bf16(ak0, aq0, sc[kt], 0, 0, 0);
            sc[kt] = __builtin_amdgcn_mfma_f32_16x16x32_bf16(ak1, aq1, sc[kt], 0, 0, 0);
        }
        __builtin_amdgcn_s_setprio(0);

        // ---- PV(t-1): independent of softmax(t) -> overlaps the VALU phase ----
        if (it > 0) {
            const __hip_bfloat16* Vc = Vsb + ((it - 1) & 1) * 2048;
            __builtin_amdgcn_s_setprio(1);
            lacc = __builtin_amdgcn_mfma_f32_16x16x32_bf16(ap_prev, ones, lacc, 0, 0, 0);
#pragma unroll
            for (int tt = 0; tt < 4; tt++) {
                const int d = tt * 16 + m16;
                short8 bv = *(const short8*)&Vc[d * 32 + vsl];
                o[tt] = __builtin_amdgcn_mfma_f32_16x16x32_bf16(ap_prev, bv, o[tt], 0, 0, 0);
            }
            __builtin_amdgcn_s_setprio(0);
        }

        // ---- softmax numerator (in-register) + pack to bf16 dword pairs ----
        unsigned dk[2][2];
#pragma unroll
        for (int kt = 0; kt < 2; kt++) {
            floatx4 wv = *(const floatx4*)&wsm[ko + k0 + kt * 16 + quad * 4];
            float p0 = __builtin_amdgcn_exp2f(__builtin_fmaf(sc[kt][0], scale2, wv[0]));
            float p1 = __builtin_amdgcn_exp2f(__builtin_fmaf(sc[kt][1], scale2, wv[1]));
            float p2 = __builtin_amdgcn_exp2f(__builtin_fmaf(sc[kt][2], scale2, wv[2]));
            float p3 = __builtin_amdgcn_exp2f(__builtin_fmaf(sc[kt][3], scale2, wv[3]));
            dk[kt][0] = pk2(p0, p1);
            dk[kt][1] = pk2(p2, p3);
        }

        // ---- chunk exchange with lane^16 (quad^1): assemble chunk C(quad) ----
        unsigned s0 = e ? dk[0][0] : dk[1][0];
        unsigned s1 = e ? dk[0][1] : dk[1][1];
        unsigned r0 = (unsigned)__builtin_amdgcn_ds_swizzle((int)s0, 0x401F);
        unsigned r1 = (unsigned)__builtin_amdgcn_ds_swizzle((int)s1, 0x401F);
        intx4 wa;
        wa[0] = (int)(e ? r0 : dk[0][0]);   // keys 8C+0,1
        wa[1] = (int)(e ? r1 : dk[0][1]);   // keys 8C+2,3
        wa[2] = (int)(e ? dk[1][0] : r0);   // keys 8C+4,5
        wa[3] = (int)(e ? dk[1][1] : r1);   // keys 8C+6,7
        ap_prev = *(short8*)&wa;

        __syncthreads();  // drains DMA (vmcnt) + barrier: K(t+1)/V(t) ready, bufs reusable
    }

    // epilogue: PV of the last tile
    {
        const __hip_bfloat16* Vc = Vsb + ((NIT - 1) & 1) * 2048;
        lacc = __builtin_amdgcn_mfma_f32_16x16x32_bf16(ap_prev, ones, lacc, 0, 0, 0);
#pragma unroll
        for (int tt = 0; tt < 4; tt++) {
            const int d = tt * 16 + m16;
            short8 bv = *(const short8*)&Vc[d * 32 + vsl];
            o[tt] = __builtin_amdgcn_mfma_f32_16x16x32_bf16(ap_prev, bv, o[tt], 0, 0, 0);
        }
    }
    __syncthreads();  // all waves done with V buffers before merge reuses smem

    // ---- merge the two key-halves (fixed-max => partials are additive) ----
    float* xch = (float*)smem;
    const int xi = (tw * 64 + lane) * 21;
    if (team == 1) {
#pragma unroll
        for (int tt = 0; tt < 4; tt++)
#pragma unroll
            for (int r = 0; r < 4; r++) xch[xi + tt * 4 + r] = o[tt][r];
#pragma unroll
        for (int r = 0; r < 4; r++) xch[xi + 16 + r] = lacc[r];
    }
    __syncthreads();
    if (team == 0) {
        float li[4];
#pragma unroll
        for (int r = 0; r < 4; r++) li[r] = 1.0f / (lacc[r] + xch[xi + 16 + r]);
#pragma unroll
        for (int tt = 0; tt < 4; tt++)
#pragma unroll
            for (int r = 0; r < 4; r++) {
                int srow = qbase + quad * 4 + r;
                int d = tt * 16 + m16;
                float v = (o[tt][r] + xch[xi + tt * 4 + r]) * li[r];
                ctx[((size_t)b * S_LEN + srow) * DMODEL + h * HD + d] = __float2bfloat16(v);
            }
    }
}

extern "C" void kernel_launch(void* const* d_in, const int* in_sizes, int n_in,
                              void* d_out, int out_size, void* d_ws, size_t ws_size,
                              hipStream_t stream) {
    (void)in_sizes; (void)n_in; (void)out_size; (void)ws_size;
    const float* hidden = (const float*)d_in[0];  // [2,2048,1024] fp32
    const float* mask   = (const float*)d_in[1];  // [2,1,1,2048] fp32
    const float* Wqkv   = (const float*)d_in[2];  // [1024,3072] fp32 [in,out]
    const float* bqkv   = (const float*)d_in[3];  // [3072] fp32
    const float* Wproj  = (const float*)d_in[4];  // [1024,1024] fp32 [in,out]
    const float* bproj  = (const float*)d_in[5];  // [1024] fp32
    float* out = (float*)d_out;                   // fp32 output

    // ---- workspace layout ----
    __hip_bfloat16* ws = (__hip_bfloat16*)d_ws;
    const size_t Q4 = 4u * 1024 * 1024;
    __hip_bfloat16* Qp      = ws;
    __hip_bfloat16* Kp      = ws + 1 * Q4;
    __hip_bfloat16* Vt      = ws + 2 * Q4;
    __hip_bfloat16* hid_bf  = ws + 3 * Q4;
    __hip_bfloat16* ctx     = ws + 3 * Q4;                    // overlaps hid_bf (disjoint lifetime)
    __hip_bfloat16* Wqkv_t  = ws + 4 * Q4;                    // 3M elems
    __hip_bfloat16* Wproj_t = ws + 4 * Q4 + 3u * 1024 * 1024; // 1M elems (no alias)

    // prep: cvt (2048) + Wqkv transpose (3072) + Wproj transpose (1024)
    prep_kernel<<<dim3(6144), 256, 0, stream>>>(hidden, hid_bf, Wqkv, Wqkv_t, Wproj, Wproj_t);

    // QKV projection + scatter: M=4096, N=3072, K=1024, 128x128 tiles (r11 config)
    gemm128<<<dim3(3072 / 128, 4096 / 128), 256, 0, stream>>>(
        hid_bf, Wqkv_t, bqkv, nullptr, Qp, Kp, Vt, BATCH * S_LEN, 3 * DMODEL, DMODEL, 1);

    // attn v11 (PV(t-1) ∥ QK(t) pipeline)
    attn_kernel<<<dim3(BATCH * NH, S_LEN / 64), 512, 0, stream>>>(Qp, Kp, Vt, mask, ctx);

    // output projection: M=4096, N=1024, K=1024 -> fp32 out, 64x64 tiles (1024 blocks)
    gemm64<<<dim3(1024 / 64, 4096 / 64), 256, 0, stream>>>(
        ctx, Wproj_t, bproj, out, BATCH * S_LEN, DMODEL, DMODEL);
}

// Round 15
// 210.949 us; speedup vs baseline: 1.0284x; 1.0158x over previous
//
#include <hip/hip_runtime.h>
#include <hip/hip_bf16.h>

typedef short short8 __attribute__((ext_vector_type(8)));
typedef float floatx4 __attribute__((ext_vector_type(4)));
typedef int intx4 __attribute__((ext_vector_type(4)));
typedef int intx2 __attribute__((ext_vector_type(2)));

#define S_LEN 2048
#define DMODEL 1024
#define NH 16
#define HD 64
#define BATCH 2

static __device__ __forceinline__ short f2bf(float x) {
    __hip_bfloat16 h = __float2bfloat16(x);
    return *(short*)&h;
}

static __device__ __forceinline__ unsigned pk2(float lo, float hi) {
    // packed bf16 pair; compiler fuses to v_cvt_pk_bf16_f32 (m240: don't hand-asm)
    unsigned a = (unsigned)(unsigned short)f2bf(lo);
    unsigned b = (unsigned)(unsigned short)f2bf(hi);
    return a | (b << 16);
}

// async 16B global->LDS (wave-uniform LDS base + lane*16 contract)
static __device__ __forceinline__ void async_ld16(const __hip_bfloat16* g, __hip_bfloat16* l) {
    __builtin_amdgcn_global_load_lds(
        (const __attribute__((address_space(1))) unsigned int*)g,
        (__attribute__((address_space(3))) unsigned int*)l, 16, 0, 0);
}

// ---------------- fused prep: cvt (0..2047) + Wqkv transpose (2048..5119) + Wproj transpose (5120..6143) ----------------
// r10 lesson: fusing the Wproj transpose INTO attn inflated the attn dispatch +9.3us
// (CU-slot competition). Wproj_t has its own workspace sub-slot so it runs here.
__global__ __launch_bounds__(256) void prep_kernel(const float* __restrict__ X,
                                                   __hip_bfloat16* __restrict__ Y,
                                                   const float* __restrict__ W,
                                                   __hip_bfloat16* __restrict__ Wt,
                                                   const float* __restrict__ Wp,
                                                   __hip_bfloat16* __restrict__ Wpt) {
    const int bid = blockIdx.x;
    const int t = threadIdx.x;
    if (bid < 2048) {
        // cvt: hidden fp32 -> bf16, 2048 floats per block
        int i = (bid * 256 + t) * 8;
        floatx4 f0 = *(const floatx4*)&X[i];
        floatx4 f1 = *(const floatx4*)&X[i + 4];
        short8 s;
        s[0] = f2bf(f0[0]); s[1] = f2bf(f0[1]); s[2] = f2bf(f0[2]); s[3] = f2bf(f0[3]);
        s[4] = f2bf(f1[0]); s[5] = f2bf(f1[1]); s[6] = f2bf(f1[2]); s[7] = f2bf(f1[3]);
        *(short8*)&Y[i] = s;
    } else if (bid < 5120) {
        // Wqkv transpose+downcast: Wt[N=3072][K=1024] = bf16(W[K][N])
        __shared__ float tile[32][33];
        const int tid = bid - 2048;              // 0..3071
        const int n0 = (tid % 96) * 32, k0 = (tid / 96) * 32;
        const int tx = t & 31, ty = t >> 5;      // (32,8)
        const int K = 1024, N = 3072;
#pragma unroll
        for (int i = 0; i < 32; i += 8)
            tile[ty + i][tx] = W[(size_t)(k0 + ty + i) * N + n0 + tx];
        __syncthreads();
#pragma unroll
        for (int i = 0; i < 32; i += 8)
            Wt[(size_t)(n0 + ty + i) * K + k0 + tx] = __float2bfloat16(tile[tx][ty + i]);
    } else {
        // Wproj transpose+downcast: Wpt[N=1024][K=1024] = bf16(Wp[K][N])
        __shared__ float tile[32][33];
        const int tid = bid - 5120;              // 0..1023
        const int n0 = (tid & 31) * 32, k0 = (tid >> 5) * 32;
        const int tx = t & 31, ty = t >> 5;      // (32,8)
        const int K = 1024, N = 1024;
#pragma unroll
        for (int i = 0; i < 32; i += 8)
            tile[ty + i][tx] = Wp[(size_t)(k0 + ty + i) * N + n0 + tx];
        __syncthreads();
#pragma unroll
        for (int i = 0; i < 32; i += 8)
            Wpt[(size_t)(n0 + ty + i) * K + k0 + tx] = __float2bfloat16(tile[tx][ty + i]);
    }
}

// ---------------- MFMA GEMM v4 (r8-exact): 128x128, BK=32, dbuf prefetch ----------------
// r9: depth-2 counted-vmcnt was flat-to-negative; r12: 64^2 tile regressed (lower
// arithmetic intensity ate the occupancy win). This is the best verified config.
__global__ __launch_bounds__(256) void gemm128(
    const __hip_bfloat16* __restrict__ A, const __hip_bfloat16* __restrict__ Bt,
    const float* __restrict__ bias, float* __restrict__ Cf,
    __hip_bfloat16* __restrict__ Qp, __hip_bfloat16* __restrict__ Kp,
    __hip_bfloat16* __restrict__ Vt, int M, int N, int K, int mode) {
    __shared__ __align__(16) __hip_bfloat16 As[2][128 * 32];
    __shared__ __align__(16) __hip_bfloat16 Bs[2][128 * 32];
    // XCD-chunked block swizzle (hardware round-robins flat id across 8 XCDs)
    const int gx = gridDim.x, gy = gridDim.y;
    const int flat = blockIdx.y * gx + blockIdx.x;
    const int cpx = (gx * gy) >> 3;
    const int id2 = (flat & 7) * cpx + (flat >> 3);
    const int m0 = (id2 % gy) * 128, n0 = (id2 / gy) * 128;
    const int t = threadIdx.x;
    const int wave = t >> 6, lane = t & 63;
    const int quad = lane >> 4, m16 = lane & 15;
    const int wm = (wave >> 1) * 64, wn = (wave & 1) * 64;
    const int srow = lane >> 2, scol = (lane & 3) * 8;

    const int rb0 = wave * 32, rb1 = wave * 32 + 16;
    const size_t aoff0 = (size_t)(m0 + rb0 + srow) * K + scol;
    const size_t aoff1 = (size_t)(m0 + rb1 + srow) * K + scol;
    const size_t boff0 = (size_t)(n0 + rb0 + srow) * K + scol;
    const size_t boff1 = (size_t)(n0 + rb1 + srow) * K + scol;

    // prologue: stage K-tile 0 into buffer 0
    async_ld16(&A[aoff0], &As[0][rb0 * 32]);
    async_ld16(&A[aoff1], &As[0][rb1 * 32]);
    async_ld16(&Bt[boff0], &Bs[0][rb0 * 32]);
    async_ld16(&Bt[boff1], &Bs[0][rb1 * 32]);
    __syncthreads();

    floatx4 acc[4][4] = {};
    const int NI = K >> 5;
    for (int it = 0; it < NI; ++it) {
        const int cur = it & 1;
        if (it < NI - 1) {
            const int k0 = (it + 1) * 32;
            async_ld16(&A[aoff0 + k0], &As[cur ^ 1][rb0 * 32]);
            async_ld16(&A[aoff1 + k0], &As[cur ^ 1][rb1 * 32]);
            async_ld16(&Bt[boff0 + k0], &Bs[cur ^ 1][rb0 * 32]);
            async_ld16(&Bt[boff1 + k0], &Bs[cur ^ 1][rb1 * 32]);
        }
        short8 af[4], bfr[4];
#pragma unroll
        for (int i = 0; i < 4; i++)
            af[i] = *(const short8*)&As[cur][(wm + i * 16 + m16) * 32 + quad * 8];
#pragma unroll
        for (int j = 0; j < 4; j++)
            bfr[j] = *(const short8*)&Bs[cur][(wn + j * 16 + m16) * 32 + quad * 8];
#pragma unroll
        for (int i = 0; i < 4; i++)
#pragma unroll
            for (int j = 0; j < 4; j++)
                acc[i][j] = __builtin_amdgcn_mfma_f32_16x16x32_bf16(af[i], bfr[j], acc[i][j], 0, 0, 0);
        __syncthreads();  // drains prefetch DMA + barrier: next buffer ready, cur reusable
    }
    if (mode == 0) {
#pragma unroll
        for (int i = 0; i < 4; i++)
#pragma unroll
            for (int j = 0; j < 4; j++) {
                int col = n0 + wn + j * 16 + m16;
                float bv = bias[col];
#pragma unroll
                for (int r = 0; r < 4; r++) {
                    int row = m0 + wm + i * 16 + quad * 4 + r;
                    Cf[(size_t)row * N + col] = acc[i][j][r] + bv;
                }
            }
    } else if (n0 < 2 * DMODEL) {
        // Q/K scatter (32B-granule)
#pragma unroll
        for (int i = 0; i < 4; i++)
#pragma unroll
            for (int j = 0; j < 4; j++) {
                int col = n0 + wn + j * 16 + m16;
                float bv = bias[col];
#pragma unroll
                for (int r = 0; r < 4; r++) {
                    int row = m0 + wm + i * 16 + quad * 4 + r;
                    __hip_bfloat16 hv = __float2bfloat16(acc[i][j][r] + bv);
                    int tt = col >> 10, rem = col & 1023;
                    int h = rem >> 6, d = rem & 63;
                    int b = row >> 11, s = row & 2047;
                    if (tt == 0) Qp[((size_t)(b * NH + h) * S_LEN + s) * HD + d] = hv;
                    else         Kp[((size_t)(b * NH + h) * S_LEN + s) * HD + d] = hv;
                }
            }
    } else {
        // V region: per-wave LDS transpose then coalesced Vt rows.
        char* T = (char*)As;
        const int bq = m0 >> 11;         // batch (tiles never straddle: 2048%128==0)
        const int s_base = m0 & 2047;
        for (int p = 0; p < 4; p++) {
            if (wave == p) {
#pragma unroll
                for (int j = 0; j < 4; j++) {
                    const int drow = j * 16 + m16;              // d_loc = col quarter-local
                    const float bv = bias[n0 + wn + j * 16 + m16];
                    const int within = (quad & 1) * 4;          // s_loc&7 base
#pragma unroll
                    for (int i = 0; i < 4; i++) {
                        const int colc = i * 2 + (quad >> 1);   // logical s-chunk
                        const int physc = colc ^ (drow & 7);
                        intx2 v;
                        v[0] = (int)pk2(acc[i][j][0] + bv, acc[i][j][1] + bv);
                        v[1] = (int)pk2(acc[i][j][2] + bv, acc[i][j][3] + bv);
                        *(intx2*)(T + drow * 128 + physc * 16 + within * 2) = v;
                    }
                }
            }
            __syncthreads();
            {
                const int dl = t >> 2;              // 0..63
                const int sseg = (t & 3) * 16;      // 0,16,32,48
                const int c0 = (sseg >> 3) ^ (dl & 7);
                const int c1 = ((sseg >> 3) + 1) ^ (dl & 7);
                short8 a0 = *(const short8*)(T + dl * 128 + c0 * 16);
                short8 a1 = *(const short8*)(T + dl * 128 + c1 * 16);
                const int hh = (n0 - 2 * DMODEL + (p & 1) * 64) >> 6;
                const int sg = s_base + (p >> 1) * 64 + sseg;
                __hip_bfloat16* dst = &Vt[((size_t)(bq * NH + hh) * HD + dl) * S_LEN + sg];
                *(short8*)dst = a0;
                *(short8*)(dst + 8) = a1;
            }
            __syncthreads();
        }
    }
}

// ---------------- MFMA GEMM 64x64 (proj, r8-exact): dbuf, 4 blocks/CU ----------------
__global__ __launch_bounds__(256) void gemm64(
    const __hip_bfloat16* __restrict__ A, const __hip_bfloat16* __restrict__ Bt,
    const float* __restrict__ bias, float* __restrict__ Cf, int M, int N, int K) {
    __shared__ __align__(16) __hip_bfloat16 As[2][64 * 32];
    __shared__ __align__(16) __hip_bfloat16 Bs[2][64 * 32];
    const int gx = gridDim.x, gy = gridDim.y;
    const int flat = blockIdx.y * gx + blockIdx.x;
    const int cpx = (gx * gy) >> 3;
    const int id2 = (flat & 7) * cpx + (flat >> 3);
    const int m0 = (id2 % gy) * 64, n0 = (id2 / gy) * 64;
    const int t = threadIdx.x;
    const int wave = t >> 6, lane = t & 63;
    const int quad = lane >> 4, m16 = lane & 15;
    const int srow = lane >> 2, scol = (lane & 3) * 8;

    const int rb = wave * 16;
    const size_t aoff = (size_t)(m0 + rb + srow) * K + scol;
    const size_t boff = (size_t)(n0 + rb + srow) * K + scol;

    async_ld16(&A[aoff], &As[0][rb * 32]);
    async_ld16(&Bt[boff], &Bs[0][rb * 32]);
    __syncthreads();

    floatx4 acc[4] = {};
    const int NI = K >> 5;
    for (int it = 0; it < NI; ++it) {
        const int cur = it & 1;
        if (it < NI - 1) {
            const int k0 = (it + 1) * 32;
            async_ld16(&A[aoff + k0], &As[cur ^ 1][rb * 32]);
            async_ld16(&Bt[boff + k0], &Bs[cur ^ 1][rb * 32]);
        }
        short8 af[4];
#pragma unroll
        for (int i = 0; i < 4; i++)
            af[i] = *(const short8*)&As[cur][(i * 16 + m16) * 32 + quad * 8];
        short8 bfr = *(const short8*)&Bs[cur][(wave * 16 + m16) * 32 + quad * 8];
#pragma unroll
        for (int i = 0; i < 4; i++)
            acc[i] = __builtin_amdgcn_mfma_f32_16x16x32_bf16(af[i], bfr, acc[i], 0, 0, 0);
        __syncthreads();
    }
    {
        const int col = n0 + wave * 16 + m16;
        const float bv = bias[col];
#pragma unroll
        for (int i = 0; i < 4; i++)
#pragma unroll
            for (int r = 0; r < 4; r++) {
                int row = m0 + i * 16 + quad * 4 + r;
                Cf[(size_t)row * N + col] = acc[i][r] + bv;
            }
    }
}

// ---------------- MFMA flash attention v9 (r8-exact, verified 57.3 us 3x): split-K, 8 waves ----------------
// r7 (32q/wave): -LDS traffic but -occupancy -> regressed. r10 (fused transpose):
// CU competition -> regressed. r14 (PV(t-1) pipeline): register lifetime + reordered
// traffic -> regressed. This latency-bound config is the verified local optimum.
__global__ __launch_bounds__(512, 8) void attn_kernel(
    const __hip_bfloat16* __restrict__ Q,   // [B,H,S,HD]
    const __hip_bfloat16* __restrict__ K,   // [B,H,S,HD]
    const __hip_bfloat16* __restrict__ Vt,  // [B,H,HD,S]
    const float* __restrict__ mask,         // [B,S] additive fp32
    __hip_bfloat16* __restrict__ ctx) {     // [B,S,D]
    __shared__ __align__(16) __hip_bfloat16 smem[16384];  // 32 KB K/V dbuf + merge
    __shared__ float wsm[S_LEN];                          // 8 KB mask table
    const int bh = blockIdx.x;
    const int b = bh >> 4, h = bh & 15;
    const int t = threadIdx.x, wave = t >> 6, lane = t & 63;
    const int team = wave >> 2, tw = wave & 3;
    const int quad = lane >> 4, m16 = lane & 15;
    const int qbase = blockIdx.y * 64 + tw * 16;
    const int ko = team * (S_LEN / 2);      // this team's key offset
    const __hip_bfloat16* Qh = Q + (size_t)bh * S_LEN * HD;
    const __hip_bfloat16* Kh = K + (size_t)bh * S_LEN * HD;
    const __hip_bfloat16* Vh = Vt + (size_t)bh * HD * S_LEN;
    const float* mb = mask + (size_t)b * S_LEN;
    const float LOG2E = 1.44269504f;
    const float scale2 = 0.125f * LOG2E;    // softmax scale pre-folded with log2(e)
    const float M_FIX2 = 20.0f * LOG2E;     // fixed-max bias (cancels in o/li)

    __hip_bfloat16* Ksb = smem + team * 8192;          // 2 bufs x 2048 elems
    __hip_bfloat16* Vsb = smem + team * 8192 + 4096;   // 2 bufs x 2048 elems

    // mask table: w[s] = mask[s]*log2e - M_FIX2
    {
        floatx4 mv = *(const floatx4*)&mb[t * 4];
        floatx4 wv;
#pragma unroll
        for (int r = 0; r < 4; r++) wv[r] = __builtin_fmaf(mv[r], LOG2E, -M_FIX2);
        *(floatx4*)&wsm[t * 4] = wv;
    }

    // DMA source offsets (per-lane, swizzled) and LDS dsts.
    const int kr = lane >> 3, kc = lane & 7;
    const int kgoff = (tw * 8 + kr) * HD + ((kc ^ kr) * 8);
    const int vr = lane >> 2, vc = lane & 3;
    const int vd = tw * 16 + vr;
    const int vgoff = vd * S_LEN + (((vc ^ ((vd >> 1) & 3))) * 8);
    __hip_bfloat16* kdst0 = Ksb + tw * 512;
    __hip_bfloat16* kdst1 = Ksb + 2048 + tw * 512;
    __hip_bfloat16* vdst0 = Vsb + tw * 512;
    __hip_bfloat16* vdst1 = Vsb + 2048 + tw * 512;

    // Q fragments (B-operand: lane m16 <-> query m16, chunk quad <-> hd)
    short8 aq0 = *(const short8*)&Qh[(size_t)(qbase + m16) * HD + quad * 8];
    short8 aq1 = *(const short8*)&Qh[(size_t)(qbase + m16) * HD + 32 + quad * 8];

    const short ONEB = (short)0x3F80;  // bf16 1.0
    const short8 ones = {ONEB, ONEB, ONEB, ONEB, ONEB, ONEB, ONEB, ONEB};

    // prologue: DMA tile 0 into buffer 0
    async_ld16(&Kh[(size_t)ko * HD + kgoff], kdst0);
    async_ld16(&Vh[(size_t)ko + vgoff], vdst0);
    __syncthreads();

    floatx4 o[4] = {};
    floatx4 lacc = {};
    const int swk = m16 & 7;                          // K fragment-read swizzle key
    const int e = quad & 1;                           // exchange parity
    const int C = ((quad & 1) << 1) | (quad >> 1);    // owned 8-key chunk (0,2,1,3)
    const int vsl = (C ^ ((m16 >> 1) & 3)) * 8;       // V-slot offset (g(d)=(m16>>1)&3)

    const int NIT = (S_LEN / 2) / 32;  // 32 iterations of 32 keys per team
    for (int it = 0; it < NIT; it++) {
        const int k0 = it * 32;
        const int cur = it & 1;
        // issue DMA for next tile into the other buffer (overlaps this iter's compute)
        if (it < NIT - 1) {
            async_ld16(&Kh[(size_t)(ko + k0 + 32) * HD + kgoff], cur ? kdst0 : kdst1);
            async_ld16(&Vh[(size_t)(ko + k0 + 32) + vgoff], cur ? vdst0 : vdst1);
        }

        // ---- QK^T (swapped): sc[kt][r] = S[key = 16kt+4quad+r][q = m16] ----
        const __hip_bfloat16* Kc = Ksb + cur * 2048;
        floatx4 sc[2] = {};
        __builtin_amdgcn_s_setprio(1);
#pragma unroll
        for (int kt = 0; kt < 2; kt++) {
            const int row = kt * 16 + m16;
            short8 ak0 = *(const short8*)&Kc[row * 64 + ((quad ^ swk) * 8)];
            short8 ak1 = *(const short8*)&Kc[row * 64 + (((quad + 4) ^ swk) * 8)];
            sc[kt] = __builtin_amdgcn_mfma_f32_16x16x32_bf16(ak0, aq0, sc[kt], 0, 0, 0);
            sc[kt] = __builtin_amdgcn_mfma_f32_16x16x32_bf16(ak1, aq1, sc[kt], 0, 0, 0);
        }
        __builtin_amdgcn_s_setprio(0);

        // ---- softmax numerator (in-register) + pack to bf16 dword pairs ----
        unsigned dk[2][2];
#pragma unroll
        for (int kt = 0; kt < 2; kt++) {
            floatx4 wv = *(const floatx4*)&wsm[ko + k0 + kt * 16 + quad * 4];
            float p0 = __builtin_amdgcn_exp2f(__builtin_fmaf(sc[kt][0], scale2, wv[0]));
            float p1 = __builtin_amdgcn_exp2f(__builtin_fmaf(sc[kt][1], scale2, wv[1]));
            float p2 = __builtin_amdgcn_exp2f(__builtin_fmaf(sc[kt][2], scale2, wv[2]));
            float p3 = __builtin_amdgcn_exp2f(__builtin_fmaf(sc[kt][3], scale2, wv[3]));
            dk[kt][0] = pk2(p0, p1);
            dk[kt][1] = pk2(p2, p3);
        }

        // ---- chunk exchange with lane^16 (quad^1): assemble chunk C(quad) ----
        unsigned s0 = e ? dk[0][0] : dk[1][0];
        unsigned s1 = e ? dk[0][1] : dk[1][1];
        unsigned r0 = (unsigned)__builtin_amdgcn_ds_swizzle((int)s0, 0x401F);
        unsigned r1 = (unsigned)__builtin_amdgcn_ds_swizzle((int)s1, 0x401F);
        intx4 wa;
        wa[0] = (int)(e ? r0 : dk[0][0]);   // keys 8C+0,1
        wa[1] = (int)(e ? r1 : dk[0][1]);   // keys 8C+2,3
        wa[2] = (int)(e ? dk[1][0] : r0);   // keys 8C+4,5
        wa[3] = (int)(e ? dk[1][1] : r1);   // keys 8C+6,7
        short8 ap = *(short8*)&wa;

        // ---- PV + row-sum (ones); V-side reads the SAME chunk C(quad) ----
        const __hip_bfloat16* Vc = Vsb + cur * 2048;
        __builtin_amdgcn_s_setprio(1);
        lacc = __builtin_amdgcn_mfma_f32_16x16x32_bf16(ap, ones, lacc, 0, 0, 0);
#pragma unroll
        for (int tt = 0; tt < 4; tt++) {
            const int d = tt * 16 + m16;
            short8 bv = *(const short8*)&Vc[d * 32 + vsl];
            o[tt] = __builtin_amdgcn_mfma_f32_16x16x32_bf16(ap, bv, o[tt], 0, 0, 0);
        }
        __builtin_amdgcn_s_setprio(0);
        __syncthreads();  // drains DMA (vmcnt) + barrier: next buffer ready, cur reusable
    }

    // ---- merge the two key-halves (fixed-max => partials are additive) ----
    float* xch = (float*)smem;
    const int xi = (tw * 64 + lane) * 21;
    if (team == 1) {
#pragma unroll
        for (int tt = 0; tt < 4; tt++)
#pragma unroll
            for (int r = 0; r < 4; r++) xch[xi + tt * 4 + r] = o[tt][r];
#pragma unroll
        for (int r = 0; r < 4; r++) xch[xi + 16 + r] = lacc[r];
    }
    __syncthreads();
    if (team == 0) {
        float li[4];
#pragma unroll
        for (int r = 0; r < 4; r++) li[r] = 1.0f / (lacc[r] + xch[xi + 16 + r]);
#pragma unroll
        for (int tt = 0; tt < 4; tt++)
#pragma unroll
            for (int r = 0; r < 4; r++) {
                int srow = qbase + quad * 4 + r;
                int d = tt * 16 + m16;
                float v = (o[tt][r] + xch[xi + tt * 4 + r]) * li[r];
                ctx[((size_t)b * S_LEN + srow) * DMODEL + h * HD + d] = __float2bfloat16(v);
            }
    }
}

extern "C" void kernel_launch(void* const* d_in, const int* in_sizes, int n_in,
                              void* d_out, int out_size, void* d_ws, size_t ws_size,
                              hipStream_t stream) {
    (void)in_sizes; (void)n_in; (void)out_size; (void)ws_size;
    const float* hidden = (const float*)d_in[0];  // [2,2048,1024] fp32
    const float* mask   = (const float*)d_in[1];  // [2,1,1,2048] fp32
    const float* Wqkv   = (const float*)d_in[2];  // [1024,3072] fp32 [in,out]
    const float* bqkv   = (const float*)d_in[3];  // [3072] fp32
    const float* Wproj  = (const float*)d_in[4];  // [1024,1024] fp32 [in,out]
    const float* bproj  = (const float*)d_in[5];  // [1024] fp32
    float* out = (float*)d_out;                   // fp32 output

    // ---- workspace layout ----
    __hip_bfloat16* ws = (__hip_bfloat16*)d_ws;
    const size_t Q4 = 4u * 1024 * 1024;
    __hip_bfloat16* Qp      = ws;
    __hip_bfloat16* Kp      = ws + 1 * Q4;
    __hip_bfloat16* Vt      = ws + 2 * Q4;
    __hip_bfloat16* hid_bf  = ws + 3 * Q4;
    __hip_bfloat16* ctx     = ws + 3 * Q4;                    // overlaps hid_bf (disjoint lifetime)
    __hip_bfloat16* Wqkv_t  = ws + 4 * Q4;                    // 3M elems
    __hip_bfloat16* Wproj_t = ws + 4 * Q4 + 3u * 1024 * 1024; // 1M elems (no alias)

    // prep: cvt (2048) + Wqkv transpose (3072) + Wproj transpose (1024)
    prep_kernel<<<dim3(6144), 256, 0, stream>>>(hidden, hid_bf, Wqkv, Wqkv_t, Wproj, Wproj_t);

    // QKV projection + scatter: M=4096, N=3072, K=1024
    gemm128<<<dim3(3072 / 128, 4096 / 128), 256, 0, stream>>>(
        hid_bf, Wqkv_t, bqkv, nullptr, Qp, Kp, Vt, BATCH * S_LEN, 3 * DMODEL, DMODEL, 1);

    // attn (pure, verified 57.3us config)
    attn_kernel<<<dim3(BATCH * NH, S_LEN / 64), 512, 0, stream>>>(Qp, Kp, Vt, mask, ctx);

    // output projection: M=4096, N=1024, K=1024 -> fp32 out, 64x64 tiles (4 blocks/CU)
    gemm64<<<dim3(1024 / 64, 4096 / 64), 256, 0, stream>>>(
        ctx, Wproj_t, bproj, out, BATCH * S_LEN, DMODEL, DMODEL);
}

// Round 16
// 194.716 us; speedup vs baseline: 1.1142x; 1.0834x over previous
//
#include <hip/hip_runtime.h>
#include <hip/hip_bf16.h>

typedef short short8 __attribute__((ext_vector_type(8)));
typedef float floatx4 __attribute__((ext_vector_type(4)));
typedef int intx4 __attribute__((ext_vector_type(4)));
typedef int intx2 __attribute__((ext_vector_type(2)));

#define S_LEN 2048
#define DMODEL 1024
#define NH 16
#define HD 64
#define BATCH 2

static __device__ __forceinline__ short f2bf(float x) {
    __hip_bfloat16 h = __float2bfloat16(x);
    return *(short*)&h;
}

static __device__ __forceinline__ unsigned pk2(float lo, float hi) {
    // packed bf16 pair; compiler fuses to v_cvt_pk_bf16_f32 (m240: don't hand-asm)
    unsigned a = (unsigned)(unsigned short)f2bf(lo);
    unsigned b = (unsigned)(unsigned short)f2bf(hi);
    return a | (b << 16);
}

// async 16B global->LDS (wave-uniform LDS base + lane*16 contract)
static __device__ __forceinline__ void async_ld16(const __hip_bfloat16* g, __hip_bfloat16* l) {
    __builtin_amdgcn_global_load_lds(
        (const __attribute__((address_space(1))) unsigned int*)g,
        (__attribute__((address_space(3))) unsigned int*)l, 16, 0, 0);
}

// ---------------- fused prep: cvt (0..2047) + Wqkv transpose (2048..5119) + Wproj transpose (5120..6143) ----------------
__global__ __launch_bounds__(256) void prep_kernel(const float* __restrict__ X,
                                                   __hip_bfloat16* __restrict__ Y,
                                                   const float* __restrict__ W,
                                                   __hip_bfloat16* __restrict__ Wt,
                                                   const float* __restrict__ Wp,
                                                   __hip_bfloat16* __restrict__ Wpt) {
    const int bid = blockIdx.x;
    const int t = threadIdx.x;
    if (bid < 2048) {
        // cvt: hidden fp32 -> bf16, 2048 floats per block
        int i = (bid * 256 + t) * 8;
        floatx4 f0 = *(const floatx4*)&X[i];
        floatx4 f1 = *(const floatx4*)&X[i + 4];
        short8 s;
        s[0] = f2bf(f0[0]); s[1] = f2bf(f0[1]); s[2] = f2bf(f0[2]); s[3] = f2bf(f0[3]);
        s[4] = f2bf(f1[0]); s[5] = f2bf(f1[1]); s[6] = f2bf(f1[2]); s[7] = f2bf(f1[3]);
        *(short8*)&Y[i] = s;
    } else if (bid < 5120) {
        // Wqkv transpose+downcast: Wt[N=3072][K=1024] = bf16(W[K][N])
        __shared__ float tile[32][33];
        const int tid = bid - 2048;              // 0..3071
        const int n0 = (tid % 96) * 32, k0 = (tid / 96) * 32;
        const int tx = t & 31, ty = t >> 5;      // (32,8)
        const int K = 1024, N = 3072;
#pragma unroll
        for (int i = 0; i < 32; i += 8)
            tile[ty + i][tx] = W[(size_t)(k0 + ty + i) * N + n0 + tx];
        __syncthreads();
#pragma unroll
        for (int i = 0; i < 32; i += 8)
            Wt[(size_t)(n0 + ty + i) * K + k0 + tx] = __float2bfloat16(tile[tx][ty + i]);
    } else {
        // Wproj transpose+downcast: Wpt[N=1024][K=1024] = bf16(Wp[K][N])
        __shared__ float tile[32][33];
        const int tid = bid - 5120;              // 0..1023
        const int n0 = (tid & 31) * 32, k0 = (tid >> 5) * 32;
        const int tx = t & 31, ty = t >> 5;      // (32,8)
        const int K = 1024, N = 1024;
#pragma unroll
        for (int i = 0; i < 32; i += 8)
            tile[ty + i][tx] = Wp[(size_t)(k0 + ty + i) * N + n0 + tx];
        __syncthreads();
#pragma unroll
        for (int i = 0; i < 32; i += 8)
            Wpt[(size_t)(n0 + ty + i) * K + k0 + tx] = __float2bfloat16(tile[tx][ty + i]);
    }
}

// ---------------- MFMA GEMM v5: 128x128 tile, BK=32, 512 threads / 8 waves ----------------
// r15 diagnosis: QKV gemm latency-bound, grid-pinned at 3 blocks/CU = 12 waves/CU
// (Mfma 16%, VALU/HBM/Occ all idle). r12's tile-shrink failed because it halved
// arithmetic intensity; this keeps the 128^2 tile (same traffic, same LDS) and
// doubles waves/block instead: 8 waves, wave w owns a 64x32 sub-tile (pair w>>1
// owns the old wave-quarter, the two waves split its columns). Per-wave acc 64->32
// VGPR; __launch_bounds__(512,6) targets <=84 VGPR -> 3 blocks/CU = 24 waves/CU.
// V-epilogue keeps the verified quarter mapping (pair p == old wave p); readback
// is byte-identical, gated to t<256.
__global__ __launch_bounds__(512, 6) void gemm128(
    const __hip_bfloat16* __restrict__ A, const __hip_bfloat16* __restrict__ Bt,
    const float* __restrict__ bias, float* __restrict__ Cf,
    __hip_bfloat16* __restrict__ Qp, __hip_bfloat16* __restrict__ Kp,
    __hip_bfloat16* __restrict__ Vt, int M, int N, int K, int mode) {
    __shared__ __align__(16) __hip_bfloat16 As[2][128 * 32];
    __shared__ __align__(16) __hip_bfloat16 Bs[2][128 * 32];
    // XCD-chunked block swizzle (hardware round-robins flat id across 8 XCDs)
    const int gx = gridDim.x, gy = gridDim.y;
    const int flat = blockIdx.y * gx + blockIdx.x;
    const int cpx = (gx * gy) >> 3;
    const int id2 = (flat & 7) * cpx + (flat >> 3);
    const int m0 = (id2 % gy) * 128, n0 = (id2 / gy) * 128;
    const int t = threadIdx.x;
    const int wave = t >> 6, lane = t & 63;
    const int quad = lane >> 4, m16 = lane & 15;
    const int pair = wave >> 1;
    const int wm = (pair >> 1) * 64;                    // row base (M)
    const int wn = (pair & 1) * 64 + (wave & 1) * 32;   // col base (N)
    const int srow = lane >> 2, scol = (lane & 3) * 8;

    // staging: wave w stages A rows [w*16,+16) and B rows [w*16,+16) (1 KB each)
    const int rb = wave * 16;
    const size_t aoff = (size_t)(m0 + rb + srow) * K + scol;
    const size_t boff = (size_t)(n0 + rb + srow) * K + scol;

    // prologue: stage K-tile 0 into buffer 0
    async_ld16(&A[aoff], &As[0][rb * 32]);
    async_ld16(&Bt[boff], &Bs[0][rb * 32]);
    __syncthreads();

    floatx4 acc[4][2] = {};
    const int NI = K >> 5;
    for (int it = 0; it < NI; ++it) {
        const int cur = it & 1;
        if (it < NI - 1) {
            const int k0 = (it + 1) * 32;
            async_ld16(&A[aoff + k0], &As[cur ^ 1][rb * 32]);
            async_ld16(&Bt[boff + k0], &Bs[cur ^ 1][rb * 32]);
        }
        short8 af[4], bfr[2];
#pragma unroll
        for (int i = 0; i < 4; i++)
            af[i] = *(const short8*)&As[cur][(wm + i * 16 + m16) * 32 + quad * 8];
#pragma unroll
        for (int j = 0; j < 2; j++)
            bfr[j] = *(const short8*)&Bs[cur][(wn + j * 16 + m16) * 32 + quad * 8];
#pragma unroll
        for (int i = 0; i < 4; i++)
#pragma unroll
            for (int j = 0; j < 2; j++)
                acc[i][j] = __builtin_amdgcn_mfma_f32_16x16x32_bf16(af[i], bfr[j], acc[i][j], 0, 0, 0);
        __syncthreads();  // drains prefetch DMA + barrier: next buffer ready, cur reusable
    }
    if (mode == 0) {
#pragma unroll
        for (int j = 0; j < 2; j++) {
            int col = n0 + wn + j * 16 + m16;
            float bv = bias[col];
#pragma unroll
            for (int i = 0; i < 4; i++)
#pragma unroll
                for (int r = 0; r < 4; r++) {
                    int row = m0 + wm + i * 16 + quad * 4 + r;
                    Cf[(size_t)row * N + col] = acc[i][j][r] + bv;
                }
        }
    } else if (n0 < 2 * DMODEL) {
        // Q/K scatter (32B-granule)
#pragma unroll
        for (int j = 0; j < 2; j++) {
            int col = n0 + wn + j * 16 + m16;
            float bv = bias[col];
#pragma unroll
            for (int i = 0; i < 4; i++)
#pragma unroll
                for (int r = 0; r < 4; r++) {
                    int row = m0 + wm + i * 16 + quad * 4 + r;
                    __hip_bfloat16 hv = __float2bfloat16(acc[i][j][r] + bv);
                    int tt = col >> 10, rem = col & 1023;
                    int h = rem >> 6, d = rem & 63;
                    int b = row >> 11, s = row & 2047;
                    if (tt == 0) Qp[((size_t)(b * NH + h) * S_LEN + s) * HD + d] = hv;
                    else         Kp[((size_t)(b * NH + h) * S_LEN + s) * HD + d] = hv;
                }
        }
    } else {
        // V region: per-PAIR LDS transpose then coalesced Vt rows.
        // Quarter mapping identical to verified r8 code: phase p == old wave p
        // (rows [(p>>1)*64,+64), cols [(p&1)*64,+64)); the pair's two waves write
        // their 32-col halves; readback (t<256) is byte-identical to r8.
        char* T = (char*)As;
        const int bq = m0 >> 11;         // batch (tiles never straddle: 2048%128==0)
        const int s_base = m0 & 2047;
        for (int p = 0; p < 4; p++) {
            if (pair == p) {
#pragma unroll
                for (int j = 0; j < 2; j++) {
                    const int drow = (wave & 1) * 32 + j * 16 + m16;  // d within quarter
                    const float bv = bias[n0 + (p & 1) * 64 + drow];
                    const int within = (quad & 1) * 4;                // s&7 base
#pragma unroll
                    for (int i = 0; i < 4; i++) {
                        const int colc = i * 2 + (quad >> 1);         // logical s-chunk
                        const int physc = colc ^ (drow & 7);
                        intx2 v;
                        v[0] = (int)pk2(acc[i][j][0] + bv, acc[i][j][1] + bv);
                        v[1] = (int)pk2(acc[i][j][2] + bv, acc[i][j][3] + bv);
                        *(intx2*)(T + drow * 128 + physc * 16 + within * 2) = v;
                    }
                }
            }
            __syncthreads();
            if (t < 256) {
                const int dl = t >> 2;              // 0..63
                const int sseg = (t & 3) * 16;      // 0,16,32,48
                const int c0 = (sseg >> 3) ^ (dl & 7);
                const int c1 = ((sseg >> 3) + 1) ^ (dl & 7);
                short8 a0 = *(const short8*)(T + dl * 128 + c0 * 16);
                short8 a1 = *(const short8*)(T + dl * 128 + c1 * 16);
                const int hh = (n0 - 2 * DMODEL + (p & 1) * 64) >> 6;
                const int sg = s_base + (p >> 1) * 64 + sseg;
                __hip_bfloat16* dst = &Vt[((size_t)(bq * NH + hh) * HD + dl) * S_LEN + sg];
                *(short8*)dst = a0;
                *(short8*)(dst + 8) = a1;
            }
            __syncthreads();
        }
    }
}

// ---------------- MFMA GEMM 64x64 (proj, r8-exact): dbuf, 4 blocks/CU ----------------
__global__ __launch_bounds__(256) void gemm64(
    const __hip_bfloat16* __restrict__ A, const __hip_bfloat16* __restrict__ Bt,
    const float* __restrict__ bias, float* __restrict__ Cf, int M, int N, int K) {
    __shared__ __align__(16) __hip_bfloat16 As[2][64 * 32];
    __shared__ __align__(16) __hip_bfloat16 Bs[2][64 * 32];
    const int gx = gridDim.x, gy = gridDim.y;
    const int flat = blockIdx.y * gx + blockIdx.x;
    const int cpx = (gx * gy) >> 3;
    const int id2 = (flat & 7) * cpx + (flat >> 3);
    const int m0 = (id2 % gy) * 64, n0 = (id2 / gy) * 64;
    const int t = threadIdx.x;
    const int wave = t >> 6, lane = t & 63;
    const int quad = lane >> 4, m16 = lane & 15;
    const int srow = lane >> 2, scol = (lane & 3) * 8;

    const int rb = wave * 16;
    const size_t aoff = (size_t)(m0 + rb + srow) * K + scol;
    const size_t boff = (size_t)(n0 + rb + srow) * K + scol;

    async_ld16(&A[aoff], &As[0][rb * 32]);
    async_ld16(&Bt[boff], &Bs[0][rb * 32]);
    __syncthreads();

    floatx4 acc[4] = {};
    const int NI = K >> 5;
    for (int it = 0; it < NI; ++it) {
        const int cur = it & 1;
        if (it < NI - 1) {
            const int k0 = (it + 1) * 32;
            async_ld16(&A[aoff + k0], &As[cur ^ 1][rb * 32]);
            async_ld16(&Bt[boff + k0], &Bs[cur ^ 1][rb * 32]);
        }
        short8 af[4];
#pragma unroll
        for (int i = 0; i < 4; i++)
            af[i] = *(const short8*)&As[cur][(i * 16 + m16) * 32 + quad * 8];
        short8 bfr = *(const short8*)&Bs[cur][(wave * 16 + m16) * 32 + quad * 8];
#pragma unroll
        for (int i = 0; i < 4; i++)
            acc[i] = __builtin_amdgcn_mfma_f32_16x16x32_bf16(af[i], bfr, acc[i], 0, 0, 0);
        __syncthreads();
    }
    {
        const int col = n0 + wave * 16 + m16;
        const float bv = bias[col];
#pragma unroll
        for (int i = 0; i < 4; i++)
#pragma unroll
            for (int r = 0; r < 4; r++) {
                int row = m0 + i * 16 + quad * 4 + r;
                Cf[(size_t)row * N + col] = acc[i][r] + bv;
            }
    }
}

// ---------------- MFMA flash attention v9 (r8-exact, verified 57.3 us 4x): split-K, 8 waves ----------------
__global__ __launch_bounds__(512, 8) void attn_kernel(
    const __hip_bfloat16* __restrict__ Q,   // [B,H,S,HD]
    const __hip_bfloat16* __restrict__ K,   // [B,H,S,HD]
    const __hip_bfloat16* __restrict__ Vt,  // [B,H,HD,S]
    const float* __restrict__ mask,         // [B,S] additive fp32
    __hip_bfloat16* __restrict__ ctx) {     // [B,S,D]
    __shared__ __align__(16) __hip_bfloat16 smem[16384];  // 32 KB K/V dbuf + merge
    __shared__ float wsm[S_LEN];                          // 8 KB mask table
    const int bh = blockIdx.x;
    const int b = bh >> 4, h = bh & 15;
    const int t = threadIdx.x, wave = t >> 6, lane = t & 63;
    const int team = wave >> 2, tw = wave & 3;
    const int quad = lane >> 4, m16 = lane & 15;
    const int qbase = blockIdx.y * 64 + tw * 16;
    const int ko = team * (S_LEN / 2);      // this team's key offset
    const __hip_bfloat16* Qh = Q + (size_t)bh * S_LEN * HD;
    const __hip_bfloat16* Kh = K + (size_t)bh * S_LEN * HD;
    const __hip_bfloat16* Vh = Vt + (size_t)bh * HD * S_LEN;
    const float* mb = mask + (size_t)b * S_LEN;
    const float LOG2E = 1.44269504f;
    const float scale2 = 0.125f * LOG2E;    // softmax scale pre-folded with log2(e)
    const float M_FIX2 = 20.0f * LOG2E;     // fixed-max bias (cancels in o/li)

    __hip_bfloat16* Ksb = smem + team * 8192;          // 2 bufs x 2048 elems
    __hip_bfloat16* Vsb = smem + team * 8192 + 4096;   // 2 bufs x 2048 elems

    // mask table: w[s] = mask[s]*log2e - M_FIX2
    {
        floatx4 mv = *(const floatx4*)&mb[t * 4];
        floatx4 wv;
#pragma unroll
        for (int r = 0; r < 4; r++) wv[r] = __builtin_fmaf(mv[r], LOG2E, -M_FIX2);
        *(floatx4*)&wsm[t * 4] = wv;
    }

    // DMA source offsets (per-lane, swizzled) and LDS dsts.
    const int kr = lane >> 3, kc = lane & 7;
    const int kgoff = (tw * 8 + kr) * HD + ((kc ^ kr) * 8);
    const int vr = lane >> 2, vc = lane & 3;
    const int vd = tw * 16 + vr;
    const int vgoff = vd * S_LEN + (((vc ^ ((vd >> 1) & 3))) * 8);
    __hip_bfloat16* kdst0 = Ksb + tw * 512;
    __hip_bfloat16* kdst1 = Ksb + 2048 + tw * 512;
    __hip_bfloat16* vdst0 = Vsb + tw * 512;
    __hip_bfloat16* vdst1 = Vsb + 2048 + tw * 512;

    // Q fragments (B-operand: lane m16 <-> query m16, chunk quad <-> hd)
    short8 aq0 = *(const short8*)&Qh[(size_t)(qbase + m16) * HD + quad * 8];
    short8 aq1 = *(const short8*)&Qh[(size_t)(qbase + m16) * HD + 32 + quad * 8];

    const short ONEB = (short)0x3F80;  // bf16 1.0
    const short8 ones = {ONEB, ONEB, ONEB, ONEB, ONEB, ONEB, ONEB, ONEB};

    // prologue: DMA tile 0 into buffer 0
    async_ld16(&Kh[(size_t)ko * HD + kgoff], kdst0);
    async_ld16(&Vh[(size_t)ko + vgoff], vdst0);
    __syncthreads();

    floatx4 o[4] = {};
    floatx4 lacc = {};
    const int swk = m16 & 7;                          // K fragment-read swizzle key
    const int e = quad & 1;                           // exchange parity
    const int C = ((quad & 1) << 1) | (quad >> 1);    // owned 8-key chunk (0,2,1,3)
    const int vsl = (C ^ ((m16 >> 1) & 3)) * 8;       // V-slot offset (g(d)=(m16>>1)&3)

    const int NIT = (S_LEN / 2) / 32;  // 32 iterations of 32 keys per team
    for (int it = 0; it < NIT; it++) {
        const int k0 = it * 32;
        const int cur = it & 1;
        // issue DMA for next tile into the other buffer (overlaps this iter's compute)
        if (it < NIT - 1) {
            async_ld16(&Kh[(size_t)(ko + k0 + 32) * HD + kgoff], cur ? kdst0 : kdst1);
            async_ld16(&Vh[(size_t)(ko + k0 + 32) + vgoff], cur ? vdst0 : vdst1);
        }

        // ---- QK^T (swapped): sc[kt][r] = S[key = 16kt+4quad+r][q = m16] ----
        const __hip_bfloat16* Kc = Ksb + cur * 2048;
        floatx4 sc[2] = {};
        __builtin_amdgcn_s_setprio(1);
#pragma unroll
        for (int kt = 0; kt < 2; kt++) {
            const int row = kt * 16 + m16;
            short8 ak0 = *(const short8*)&Kc[row * 64 + ((quad ^ swk) * 8)];
            short8 ak1 = *(const short8*)&Kc[row * 64 + (((quad + 4) ^ swk) * 8)];
            sc[kt] = __builtin_amdgcn_mfma_f32_16x16x32_bf16(ak0, aq0, sc[kt], 0, 0, 0);
            sc[kt] = __builtin_amdgcn_mfma_f32_16x16x32_bf16(ak1, aq1, sc[kt], 0, 0, 0);
        }
        __builtin_amdgcn_s_setprio(0);

        // ---- softmax numerator (in-register) + pack to bf16 dword pairs ----
        unsigned dk[2][2];
#pragma unroll
        for (int kt = 0; kt < 2; kt++) {
            floatx4 wv = *(const floatx4*)&wsm[ko + k0 + kt * 16 + quad * 4];
            float p0 = __builtin_amdgcn_exp2f(__builtin_fmaf(sc[kt][0], scale2, wv[0]));
            float p1 = __builtin_amdgcn_exp2f(__builtin_fmaf(sc[kt][1], scale2, wv[1]));
            float p2 = __builtin_amdgcn_exp2f(__builtin_fmaf(sc[kt][2], scale2, wv[2]));
            float p3 = __builtin_amdgcn_exp2f(__builtin_fmaf(sc[kt][3], scale2, wv[3]));
            dk[kt][0] = pk2(p0, p1);
            dk[kt][1] = pk2(p2, p3);
        }

        // ---- chunk exchange with lane^16 (quad^1): assemble chunk C(quad) ----
        unsigned s0 = e ? dk[0][0] : dk[1][0];
        unsigned s1 = e ? dk[0][1] : dk[1][1];
        unsigned r0 = (unsigned)__builtin_amdgcn_ds_swizzle((int)s0, 0x401F);
        unsigned r1 = (unsigned)__builtin_amdgcn_ds_swizzle((int)s1, 0x401F);
        intx4 wa;
        wa[0] = (int)(e ? r0 : dk[0][0]);   // keys 8C+0,1
        wa[1] = (int)(e ? r1 : dk[0][1]);   // keys 8C+2,3
        wa[2] = (int)(e ? dk[1][0] : r0);   // keys 8C+4,5
        wa[3] = (int)(e ? dk[1][1] : r1);   // keys 8C+6,7
        short8 ap = *(short8*)&wa;

        // ---- PV + row-sum (ones); V-side reads the SAME chunk C(quad) ----
        const __hip_bfloat16* Vc = Vsb + cur * 2048;
        __builtin_amdgcn_s_setprio(1);
        lacc = __builtin_amdgcn_mfma_f32_16x16x32_bf16(ap, ones, lacc, 0, 0, 0);
#pragma unroll
        for (int tt = 0; tt < 4; tt++) {
            const int d = tt * 16 + m16;
            short8 bv = *(const short8*)&Vc[d * 32 + vsl];
            o[tt] = __builtin_amdgcn_mfma_f32_16x16x32_bf16(ap, bv, o[tt], 0, 0, 0);
        }
        __builtin_amdgcn_s_setprio(0);
        __syncthreads();  // drains DMA (vmcnt) + barrier: next buffer ready, cur reusable
    }

    // ---- merge the two key-halves (fixed-max => partials are additive) ----
    float* xch = (float*)smem;
    const int xi = (tw * 64 + lane) * 21;
    if (team == 1) {
#pragma unroll
        for (int tt = 0; tt < 4; tt++)
#pragma unroll
            for (int r = 0; r < 4; r++) xch[xi + tt * 4 + r] = o[tt][r];
#pragma unroll
        for (int r = 0; r < 4; r++) xch[xi + 16 + r] = lacc[r];
    }
    __syncthreads();
    if (team == 0) {
        float li[4];
#pragma unroll
        for (int r = 0; r < 4; r++) li[r] = 1.0f / (lacc[r] + xch[xi + 16 + r]);
#pragma unroll
        for (int tt = 0; tt < 4; tt++)
#pragma unroll
            for (int r = 0; r < 4; r++) {
                int srow = qbase + quad * 4 + r;
                int d = tt * 16 + m16;
                float v = (o[tt][r] + xch[xi + tt * 4 + r]) * li[r];
                ctx[((size_t)b * S_LEN + srow) * DMODEL + h * HD + d] = __float2bfloat16(v);
            }
    }
}

extern "C" void kernel_launch(void* const* d_in, const int* in_sizes, int n_in,
                              void* d_out, int out_size, void* d_ws, size_t ws_size,
                              hipStream_t stream) {
    (void)in_sizes; (void)n_in; (void)out_size; (void)ws_size;
    const float* hidden = (const float*)d_in[0];  // [2,2048,1024] fp32
    const float* mask   = (const float*)d_in[1];  // [2,1,1,2048] fp32
    const float* Wqkv   = (const float*)d_in[2];  // [1024,3072] fp32 [in,out]
    const float* bqkv   = (const float*)d_in[3];  // [3072] fp32
    const float* Wproj  = (const float*)d_in[4];  // [1024,1024] fp32 [in,out]
    const float* bproj  = (const float*)d_in[5];  // [1024] fp32
    float* out = (float*)d_out;                   // fp32 output

    // ---- workspace layout ----
    __hip_bfloat16* ws = (__hip_bfloat16*)d_ws;
    const size_t Q4 = 4u * 1024 * 1024;
    __hip_bfloat16* Qp      = ws;
    __hip_bfloat16* Kp      = ws + 1 * Q4;
    __hip_bfloat16* Vt      = ws + 2 * Q4;
    __hip_bfloat16* hid_bf  = ws + 3 * Q4;
    __hip_bfloat16* ctx     = ws + 3 * Q4;                    // overlaps hid_bf (disjoint lifetime)
    __hip_bfloat16* Wqkv_t  = ws + 4 * Q4;                    // 3M elems
    __hip_bfloat16* Wproj_t = ws + 4 * Q4 + 3u * 1024 * 1024; // 1M elems (no alias)

    // prep: cvt (2048) + Wqkv transpose (3072) + Wproj transpose (1024)
    prep_kernel<<<dim3(6144), 256, 0, stream>>>(hidden, hid_bf, Wqkv, Wqkv_t, Wproj, Wproj_t);

    // QKV projection + scatter: M=4096, N=3072, K=1024, 128x128 tiles, 512 threads
    gemm128<<<dim3(3072 / 128, 4096 / 128), 512, 0, stream>>>(
        hid_bf, Wqkv_t, bqkv, nullptr, Qp, Kp, Vt, BATCH * S_LEN, 3 * DMODEL, DMODEL, 1);

    // attn (pure, verified 57.3us config)
    attn_kernel<<<dim3(BATCH * NH, S_LEN / 64), 512, 0, stream>>>(Qp, Kp, Vt, mask, ctx);

    // output projection: M=4096, N=1024, K=1024 -> fp32 out, 64x64 tiles (4 blocks/CU)
    gemm64<<<dim3(1024 / 64, 4096 / 64), 256, 0, stream>>>(
        ctx, Wproj_t, bproj, out, BATCH * S_LEN, DMODEL, DMODEL);
}

// Round 17
// 188.934 us; speedup vs baseline: 1.1483x; 1.0306x over previous
//
#include <hip/hip_runtime.h>
#include <hip/hip_bf16.h>

typedef short short8 __attribute__((ext_vector_type(8)));
typedef float floatx4 __attribute__((ext_vector_type(4)));
typedef int intx4 __attribute__((ext_vector_type(4)));
typedef int intx2 __attribute__((ext_vector_type(2)));

#define S_LEN 2048
#define DMODEL 1024
#define NH 16
#define HD 64
#define BATCH 2

static __device__ __forceinline__ short f2bf(float x) {
    __hip_bfloat16 h = __float2bfloat16(x);
    return *(short*)&h;
}

static __device__ __forceinline__ unsigned pk2(float lo, float hi) {
    // packed bf16 pair; compiler fuses to v_cvt_pk_bf16_f32 (m240: don't hand-asm)
    unsigned a = (unsigned)(unsigned short)f2bf(lo);
    unsigned b = (unsigned)(unsigned short)f2bf(hi);
    return a | (b << 16);
}

// async 16B global->LDS (wave-uniform LDS base + lane*16 contract)
static __device__ __forceinline__ void async_ld16(const __hip_bfloat16* g, __hip_bfloat16* l) {
    __builtin_amdgcn_global_load_lds(
        (const __attribute__((address_space(1))) unsigned int*)g,
        (__attribute__((address_space(3))) unsigned int*)l, 16, 0, 0);
}

// ---------------- fused prep: cvt (0..2047) + Wqkv transpose (2048..5119) + Wproj transpose (5120..6143) ----------------
__global__ __launch_bounds__(256) void prep_kernel(const float* __restrict__ X,
                                                   __hip_bfloat16* __restrict__ Y,
                                                   const float* __restrict__ W,
                                                   __hip_bfloat16* __restrict__ Wt,
                                                   const float* __restrict__ Wp,
                                                   __hip_bfloat16* __restrict__ Wpt) {
    const int bid = blockIdx.x;
    const int t = threadIdx.x;
    if (bid < 2048) {
        // cvt: hidden fp32 -> bf16, 2048 floats per block
        int i = (bid * 256 + t) * 8;
        floatx4 f0 = *(const floatx4*)&X[i];
        floatx4 f1 = *(const floatx4*)&X[i + 4];
        short8 s;
        s[0] = f2bf(f0[0]); s[1] = f2bf(f0[1]); s[2] = f2bf(f0[2]); s[3] = f2bf(f0[3]);
        s[4] = f2bf(f1[0]); s[5] = f2bf(f1[1]); s[6] = f2bf(f1[2]); s[7] = f2bf(f1[3]);
        *(short8*)&Y[i] = s;
    } else if (bid < 5120) {
        // Wqkv transpose+downcast: Wt[N=3072][K=1024] = bf16(W[K][N])
        __shared__ float tile[32][33];
        const int tid = bid - 2048;              // 0..3071
        const int n0 = (tid % 96) * 32, k0 = (tid / 96) * 32;
        const int tx = t & 31, ty = t >> 5;      // (32,8)
        const int K = 1024, N = 3072;
#pragma unroll
        for (int i = 0; i < 32; i += 8)
            tile[ty + i][tx] = W[(size_t)(k0 + ty + i) * N + n0 + tx];
        __syncthreads();
#pragma unroll
        for (int i = 0; i < 32; i += 8)
            Wt[(size_t)(n0 + ty + i) * K + k0 + tx] = __float2bfloat16(tile[tx][ty + i]);
    } else {
        // Wproj transpose+downcast: Wpt[N=1024][K=1024] = bf16(Wp[K][N])
        __shared__ float tile[32][33];
        const int tid = bid - 5120;              // 0..1023
        const int n0 = (tid & 31) * 32, k0 = (tid >> 5) * 32;
        const int tx = t & 31, ty = t >> 5;      // (32,8)
        const int K = 1024, N = 1024;
#pragma unroll
        for (int i = 0; i < 32; i += 8)
            tile[ty + i][tx] = Wp[(size_t)(k0 + ty + i) * N + n0 + tx];
        __syncthreads();
#pragma unroll
        for (int i = 0; i < 32; i += 8)
            Wpt[(size_t)(n0 + ty + i) * K + k0 + tx] = __float2bfloat16(tile[tx][ty + i]);
    }
}

// ---------------- MFMA GEMM v5 (r16-exact): 128x128 tile, BK=32, 512 threads / 8 waves ----------------
// r16 result: 8 waves on the same 128^2 tile (constant arithmetic intensity,
// 2x waves/CU) cut the QKV gemm below the attn cutoff; total 210.9 -> 194.7.
__global__ __launch_bounds__(512, 6) void gemm128(
    const __hip_bfloat16* __restrict__ A, const __hip_bfloat16* __restrict__ Bt,
    const float* __restrict__ bias, float* __restrict__ Cf,
    __hip_bfloat16* __restrict__ Qp, __hip_bfloat16* __restrict__ Kp,
    __hip_bfloat16* __restrict__ Vt, int M, int N, int K, int mode) {
    __shared__ __align__(16) __hip_bfloat16 As[2][128 * 32];
    __shared__ __align__(16) __hip_bfloat16 Bs[2][128 * 32];
    // XCD-chunked block swizzle (hardware round-robins flat id across 8 XCDs)
    const int gx = gridDim.x, gy = gridDim.y;
    const int flat = blockIdx.y * gx + blockIdx.x;
    const int cpx = (gx * gy) >> 3;
    const int id2 = (flat & 7) * cpx + (flat >> 3);
    const int m0 = (id2 % gy) * 128, n0 = (id2 / gy) * 128;
    const int t = threadIdx.x;
    const int wave = t >> 6, lane = t & 63;
    const int quad = lane >> 4, m16 = lane & 15;
    const int pair = wave >> 1;
    const int wm = (pair >> 1) * 64;                    // row base (M)
    const int wn = (pair & 1) * 64 + (wave & 1) * 32;   // col base (N)
    const int srow = lane >> 2, scol = (lane & 3) * 8;

    // staging: wave w stages A rows [w*16,+16) and B rows [w*16,+16) (1 KB each)
    const int rb = wave * 16;
    const size_t aoff = (size_t)(m0 + rb + srow) * K + scol;
    const size_t boff = (size_t)(n0 + rb + srow) * K + scol;

    // prologue: stage K-tile 0 into buffer 0
    async_ld16(&A[aoff], &As[0][rb * 32]);
    async_ld16(&Bt[boff], &Bs[0][rb * 32]);
    __syncthreads();

    floatx4 acc[4][2] = {};
    const int NI = K >> 5;
    for (int it = 0; it < NI; ++it) {
        const int cur = it & 1;
        if (it < NI - 1) {
            const int k0 = (it + 1) * 32;
            async_ld16(&A[aoff + k0], &As[cur ^ 1][rb * 32]);
            async_ld16(&Bt[boff + k0], &Bs[cur ^ 1][rb * 32]);
        }
        short8 af[4], bfr[2];
#pragma unroll
        for (int i = 0; i < 4; i++)
            af[i] = *(const short8*)&As[cur][(wm + i * 16 + m16) * 32 + quad * 8];
#pragma unroll
        for (int j = 0; j < 2; j++)
            bfr[j] = *(const short8*)&Bs[cur][(wn + j * 16 + m16) * 32 + quad * 8];
#pragma unroll
        for (int i = 0; i < 4; i++)
#pragma unroll
            for (int j = 0; j < 2; j++)
                acc[i][j] = __builtin_amdgcn_mfma_f32_16x16x32_bf16(af[i], bfr[j], acc[i][j], 0, 0, 0);
        __syncthreads();  // drains prefetch DMA + barrier: next buffer ready, cur reusable
    }
    if (mode == 0) {
#pragma unroll
        for (int j = 0; j < 2; j++) {
            int col = n0 + wn + j * 16 + m16;
            float bv = bias[col];
#pragma unroll
            for (int i = 0; i < 4; i++)
#pragma unroll
                for (int r = 0; r < 4; r++) {
                    int row = m0 + wm + i * 16 + quad * 4 + r;
                    Cf[(size_t)row * N + col] = acc[i][j][r] + bv;
                }
        }
    } else if (n0 < 2 * DMODEL) {
        // Q/K scatter (32B-granule)
#pragma unroll
        for (int j = 0; j < 2; j++) {
            int col = n0 + wn + j * 16 + m16;
            float bv = bias[col];
#pragma unroll
            for (int i = 0; i < 4; i++)
#pragma unroll
                for (int r = 0; r < 4; r++) {
                    int row = m0 + wm + i * 16 + quad * 4 + r;
                    __hip_bfloat16 hv = __float2bfloat16(acc[i][j][r] + bv);
                    int tt = col >> 10, rem = col & 1023;
                    int h = rem >> 6, d = rem & 63;
                    int b = row >> 11, s = row & 2047;
                    if (tt == 0) Qp[((size_t)(b * NH + h) * S_LEN + s) * HD + d] = hv;
                    else         Kp[((size_t)(b * NH + h) * S_LEN + s) * HD + d] = hv;
                }
        }
    } else {
        // V region: per-PAIR LDS transpose then coalesced Vt rows (verified r16).
        char* T = (char*)As;
        const int bq = m0 >> 11;         // batch (tiles never straddle: 2048%128==0)
        const int s_base = m0 & 2047;
        for (int p = 0; p < 4; p++) {
            if (pair == p) {
#pragma unroll
                for (int j = 0; j < 2; j++) {
                    const int drow = (wave & 1) * 32 + j * 16 + m16;  // d within quarter
                    const float bv = bias[n0 + (p & 1) * 64 + drow];
                    const int within = (quad & 1) * 4;                // s&7 base
#pragma unroll
                    for (int i = 0; i < 4; i++) {
                        const int colc = i * 2 + (quad >> 1);         // logical s-chunk
                        const int physc = colc ^ (drow & 7);
                        intx2 v;
                        v[0] = (int)pk2(acc[i][j][0] + bv, acc[i][j][1] + bv);
                        v[1] = (int)pk2(acc[i][j][2] + bv, acc[i][j][3] + bv);
                        *(intx2*)(T + drow * 128 + physc * 16 + within * 2) = v;
                    }
                }
            }
            __syncthreads();
            if (t < 256) {
                const int dl = t >> 2;              // 0..63
                const int sseg = (t & 3) * 16;      // 0,16,32,48
                const int c0 = (sseg >> 3) ^ (dl & 7);
                const int c1 = ((sseg >> 3) + 1) ^ (dl & 7);
                short8 a0 = *(const short8*)(T + dl * 128 + c0 * 16);
                short8 a1 = *(const short8*)(T + dl * 128 + c1 * 16);
                const int hh = (n0 - 2 * DMODEL + (p & 1) * 64) >> 6;
                const int sg = s_base + (p >> 1) * 64 + sseg;
                __hip_bfloat16* dst = &Vt[((size_t)(bq * NH + hh) * HD + dl) * S_LEN + sg];
                *(short8*)dst = a0;
                *(short8*)(dst + 8) = a1;
            }
            __syncthreads();
        }
    }
}

// ---------------- MFMA GEMM 64x64 v3 (proj): 512 threads / 8 waves ----------------
// Same lever as r16's gemm128 win: 8 waves on the SAME 64x64 tile (constant
// arithmetic intensity). Wave w owns rows (w&1)*32+[0,32), cols (w>>1)*16+[0,16):
// 2 MFMA + 3 ds_read per iter. Staging simplifies to 1 async_ld16 per wave per
// buffer (waves 0-3: A rows [w*16,+16); waves 4-7: B rows [(w-4)*16,+16)).
// Grid 1024 blocks -> 4 blocks/CU x 8 waves = 32 waves/CU (was 16).
__global__ __launch_bounds__(512, 8) void gemm64(
    const __hip_bfloat16* __restrict__ A, const __hip_bfloat16* __restrict__ Bt,
    const float* __restrict__ bias, float* __restrict__ Cf, int M, int N, int K) {
    __shared__ __align__(16) __hip_bfloat16 As[2][64 * 32];
    __shared__ __align__(16) __hip_bfloat16 Bs[2][64 * 32];
    const int gx = gridDim.x, gy = gridDim.y;
    const int flat = blockIdx.y * gx + blockIdx.x;
    const int cpx = (gx * gy) >> 3;
    const int id2 = (flat & 7) * cpx + (flat >> 3);
    const int m0 = (id2 % gy) * 64, n0 = (id2 / gy) * 64;
    const int t = threadIdx.x;
    const int wave = t >> 6, lane = t & 63;
    const int quad = lane >> 4, m16 = lane & 15;
    const int rh = wave & 1, cq = wave >> 1;   // row half / col quarter
    const int srow = lane >> 2, scol = (lane & 3) * 8;

    // staging: waves 0-3 stage A rows [w*16,+16); waves 4-7 stage B rows [(w-4)*16,+16)
    const bool isA = wave < 4;
    const int rb = (wave & 3) * 16;
    const size_t goff = isA ? ((size_t)(m0 + rb + srow) * K + scol)
                            : ((size_t)(n0 + rb + srow) * K + scol);
    const __hip_bfloat16* gsrc = isA ? A : Bt;

    async_ld16(&gsrc[goff], &(isA ? As : Bs)[0][rb * 32]);
    __syncthreads();

    floatx4 acc[2] = {};
    const int NI = K >> 5;
    for (int it = 0; it < NI; ++it) {
        const int cur = it & 1;
        if (it < NI - 1) {
            const int k0 = (it + 1) * 32;
            async_ld16(&gsrc[goff + k0], &(isA ? As : Bs)[cur ^ 1][rb * 32]);
        }
        short8 af[2];
#pragma unroll
        for (int i = 0; i < 2; i++)
            af[i] = *(const short8*)&As[cur][(rh * 32 + i * 16 + m16) * 32 + quad * 8];
        short8 bfr = *(const short8*)&Bs[cur][(cq * 16 + m16) * 32 + quad * 8];
#pragma unroll
        for (int i = 0; i < 2; i++)
            acc[i] = __builtin_amdgcn_mfma_f32_16x16x32_bf16(af[i], bfr, acc[i], 0, 0, 0);
        __syncthreads();
    }
    {
        const int col = n0 + cq * 16 + m16;
        const float bv = bias[col];
#pragma unroll
        for (int i = 0; i < 2; i++)
#pragma unroll
            for (int r = 0; r < 4; r++) {
                int row = m0 + rh * 32 + i * 16 + quad * 4 + r;
                Cf[(size_t)row * N + col] = acc[i][r] + bv;
            }
    }
}

// ---------------- MFMA flash attention v9 (r8-exact, verified 57.3 us 5x): split-K, 8 waves ----------------
__global__ __launch_bounds__(512, 8) void attn_kernel(
    const __hip_bfloat16* __restrict__ Q,   // [B,H,S,HD]
    const __hip_bfloat16* __restrict__ K,   // [B,H,S,HD]
    const __hip_bfloat16* __restrict__ Vt,  // [B,H,HD,S]
    const float* __restrict__ mask,         // [B,S] additive fp32
    __hip_bfloat16* __restrict__ ctx) {     // [B,S,D]
    __shared__ __align__(16) __hip_bfloat16 smem[16384];  // 32 KB K/V dbuf + merge
    __shared__ float wsm[S_LEN];                          // 8 KB mask table
    const int bh = blockIdx.x;
    const int b = bh >> 4, h = bh & 15;
    const int t = threadIdx.x, wave = t >> 6, lane = t & 63;
    const int team = wave >> 2, tw = wave & 3;
    const int quad = lane >> 4, m16 = lane & 15;
    const int qbase = blockIdx.y * 64 + tw * 16;
    const int ko = team * (S_LEN / 2);      // this team's key offset
    const __hip_bfloat16* Qh = Q + (size_t)bh * S_LEN * HD;
    const __hip_bfloat16* Kh = K + (size_t)bh * S_LEN * HD;
    const __hip_bfloat16* Vh = Vt + (size_t)bh * HD * S_LEN;
    const float* mb = mask + (size_t)b * S_LEN;
    const float LOG2E = 1.44269504f;
    const float scale2 = 0.125f * LOG2E;    // softmax scale pre-folded with log2(e)
    const float M_FIX2 = 20.0f * LOG2E;     // fixed-max bias (cancels in o/li)

    __hip_bfloat16* Ksb = smem + team * 8192;          // 2 bufs x 2048 elems
    __hip_bfloat16* Vsb = smem + team * 8192 + 4096;   // 2 bufs x 2048 elems

    // mask table: w[s] = mask[s]*log2e - M_FIX2
    {
        floatx4 mv = *(const floatx4*)&mb[t * 4];
        floatx4 wv;
#pragma unroll
        for (int r = 0; r < 4; r++) wv[r] = __builtin_fmaf(mv[r], LOG2E, -M_FIX2);
        *(floatx4*)&wsm[t * 4] = wv;
    }

    // DMA source offsets (per-lane, swizzled) and LDS dsts.
    const int kr = lane >> 3, kc = lane & 7;
    const int kgoff = (tw * 8 + kr) * HD + ((kc ^ kr) * 8);
    const int vr = lane >> 2, vc = lane & 3;
    const int vd = tw * 16 + vr;
    const int vgoff = vd * S_LEN + (((vc ^ ((vd >> 1) & 3))) * 8);
    __hip_bfloat16* kdst0 = Ksb + tw * 512;
    __hip_bfloat16* kdst1 = Ksb + 2048 + tw * 512;
    __hip_bfloat16* vdst0 = Vsb + tw * 512;
    __hip_bfloat16* vdst1 = Vsb + 2048 + tw * 512;

    // Q fragments (B-operand: lane m16 <-> query m16, chunk quad <-> hd)
    short8 aq0 = *(const short8*)&Qh[(size_t)(qbase + m16) * HD + quad * 8];
    short8 aq1 = *(const short8*)&Qh[(size_t)(qbase + m16) * HD + 32 + quad * 8];

    const short ONEB = (short)0x3F80;  // bf16 1.0
    const short8 ones = {ONEB, ONEB, ONEB, ONEB, ONEB, ONEB, ONEB, ONEB};

    // prologue: DMA tile 0 into buffer 0
    async_ld16(&Kh[(size_t)ko * HD + kgoff], kdst0);
    async_ld16(&Vh[(size_t)ko + vgoff], vdst0);
    __syncthreads();

    floatx4 o[4] = {};
    floatx4 lacc = {};
    const int swk = m16 & 7;                          // K fragment-read swizzle key
    const int e = quad & 1;                           // exchange parity
    const int C = ((quad & 1) << 1) | (quad >> 1);    // owned 8-key chunk (0,2,1,3)
    const int vsl = (C ^ ((m16 >> 1) & 3)) * 8;       // V-slot offset (g(d)=(m16>>1)&3)

    const int NIT = (S_LEN / 2) / 32;  // 32 iterations of 32 keys per team
    for (int it = 0; it < NIT; it++) {
        const int k0 = it * 32;
        const int cur = it & 1;
        // issue DMA for next tile into the other buffer (overlaps this iter's compute)
        if (it < NIT - 1) {
            async_ld16(&Kh[(size_t)(ko + k0 + 32) * HD + kgoff], cur ? kdst0 : kdst1);
            async_ld16(&Vh[(size_t)(ko + k0 + 32) + vgoff], cur ? vdst0 : vdst1);
        }

        // ---- QK^T (swapped): sc[kt][r] = S[key = 16kt+4quad+r][q = m16] ----
        const __hip_bfloat16* Kc = Ksb + cur * 2048;
        floatx4 sc[2] = {};
        __builtin_amdgcn_s_setprio(1);
#pragma unroll
        for (int kt = 0; kt < 2; kt++) {
            const int row = kt * 16 + m16;
            short8 ak0 = *(const short8*)&Kc[row * 64 + ((quad ^ swk) * 8)];
            short8 ak1 = *(const short8*)&Kc[row * 64 + (((quad + 4) ^ swk) * 8)];
            sc[kt] = __builtin_amdgcn_mfma_f32_16x16x32_bf16(ak0, aq0, sc[kt], 0, 0, 0);
            sc[kt] = __builtin_amdgcn_mfma_f32_16x16x32_bf16(ak1, aq1, sc[kt], 0, 0, 0);
        }
        __builtin_amdgcn_s_setprio(0);

        // ---- softmax numerator (in-register) + pack to bf16 dword pairs ----
        unsigned dk[2][2];
#pragma unroll
        for (int kt = 0; kt < 2; kt++) {
            floatx4 wv = *(const floatx4*)&wsm[ko + k0 + kt * 16 + quad * 4];
            float p0 = __builtin_amdgcn_exp2f(__builtin_fmaf(sc[kt][0], scale2, wv[0]));
            float p1 = __builtin_amdgcn_exp2f(__builtin_fmaf(sc[kt][1], scale2, wv[1]));
            float p2 = __builtin_amdgcn_exp2f(__builtin_fmaf(sc[kt][2], scale2, wv[2]));
            float p3 = __builtin_amdgcn_exp2f(__builtin_fmaf(sc[kt][3], scale2, wv[3]));
            dk[kt][0] = pk2(p0, p1);
            dk[kt][1] = pk2(p2, p3);
        }

        // ---- chunk exchange with lane^16 (quad^1): assemble chunk C(quad) ----
        unsigned s0 = e ? dk[0][0] : dk[1][0];
        unsigned s1 = e ? dk[0][1] : dk[1][1];
        unsigned r0 = (unsigned)__builtin_amdgcn_ds_swizzle((int)s0, 0x401F);
        unsigned r1 = (unsigned)__builtin_amdgcn_ds_swizzle((int)s1, 0x401F);
        intx4 wa;
        wa[0] = (int)(e ? r0 : dk[0][0]);   // keys 8C+0,1
        wa[1] = (int)(e ? r1 : dk[0][1]);   // keys 8C+2,3
        wa[2] = (int)(e ? dk[1][0] : r0);   // keys 8C+4,5
        wa[3] = (int)(e ? dk[1][1] : r1);   // keys 8C+6,7
        short8 ap = *(short8*)&wa;

        // ---- PV + row-sum (ones); V-side reads the SAME chunk C(quad) ----
        const __hip_bfloat16* Vc = Vsb + cur * 2048;
        __builtin_amdgcn_s_setprio(1);
        lacc = __builtin_amdgcn_mfma_f32_16x16x32_bf16(ap, ones, lacc, 0, 0, 0);
#pragma unroll
        for (int tt = 0; tt < 4; tt++) {
            const int d = tt * 16 + m16;
            short8 bv = *(const short8*)&Vc[d * 32 + vsl];
            o[tt] = __builtin_amdgcn_mfma_f32_16x16x32_bf16(ap, bv, o[tt], 0, 0, 0);
        }
        __builtin_amdgcn_s_setprio(0);
        __syncthreads();  // drains DMA (vmcnt) + barrier: next buffer ready, cur reusable
    }

    // ---- merge the two key-halves (fixed-max => partials are additive) ----
    float* xch = (float*)smem;
    const int xi = (tw * 64 + lane) * 21;
    if (team == 1) {
#pragma unroll
        for (int tt = 0; tt < 4; tt++)
#pragma unroll
            for (int r = 0; r < 4; r++) xch[xi + tt * 4 + r] = o[tt][r];
#pragma unroll
        for (int r = 0; r < 4; r++) xch[xi + 16 + r] = lacc[r];
    }
    __syncthreads();
    if (team == 0) {
        float li[4];
#pragma unroll
        for (int r = 0; r < 4; r++) li[r] = 1.0f / (lacc[r] + xch[xi + 16 + r]);
#pragma unroll
        for (int tt = 0; tt < 4; tt++)
#pragma unroll
            for (int r = 0; r < 4; r++) {
                int srow = qbase + quad * 4 + r;
                int d = tt * 16 + m16;
                float v = (o[tt][r] + xch[xi + tt * 4 + r]) * li[r];
                ctx[((size_t)b * S_LEN + srow) * DMODEL + h * HD + d] = __float2bfloat16(v);
            }
    }
}

extern "C" void kernel_launch(void* const* d_in, const int* in_sizes, int n_in,
                              void* d_out, int out_size, void* d_ws, size_t ws_size,
                              hipStream_t stream) {
    (void)in_sizes; (void)n_in; (void)out_size; (void)ws_size;
    const float* hidden = (const float*)d_in[0];  // [2,2048,1024] fp32
    const float* mask   = (const float*)d_in[1];  // [2,1,1,2048] fp32
    const float* Wqkv   = (const float*)d_in[2];  // [1024,3072] fp32 [in,out]
    const float* bqkv   = (const float*)d_in[3];  // [3072] fp32
    const float* Wproj  = (const float*)d_in[4];  // [1024,1024] fp32 [in,out]
    const float* bproj  = (const float*)d_in[5];  // [1024] fp32
    float* out = (float*)d_out;                   // fp32 output

    // ---- workspace layout ----
    __hip_bfloat16* ws = (__hip_bfloat16*)d_ws;
    const size_t Q4 = 4u * 1024 * 1024;
    __hip_bfloat16* Qp      = ws;
    __hip_bfloat16* Kp      = ws + 1 * Q4;
    __hip_bfloat16* Vt      = ws + 2 * Q4;
    __hip_bfloat16* hid_bf  = ws + 3 * Q4;
    __hip_bfloat16* ctx     = ws + 3 * Q4;                    // overlaps hid_bf (disjoint lifetime)
    __hip_bfloat16* Wqkv_t  = ws + 4 * Q4;                    // 3M elems
    __hip_bfloat16* Wproj_t = ws + 4 * Q4 + 3u * 1024 * 1024; // 1M elems (no alias)

    // prep: cvt (2048) + Wqkv transpose (3072) + Wproj transpose (1024)
    prep_kernel<<<dim3(6144), 256, 0, stream>>>(hidden, hid_bf, Wqkv, Wqkv_t, Wproj, Wproj_t);

    // QKV projection + scatter: M=4096, N=3072, K=1024, 128x128 tiles, 512 threads
    gemm128<<<dim3(3072 / 128, 4096 / 128), 512, 0, stream>>>(
        hid_bf, Wqkv_t, bqkv, nullptr, Qp, Kp, Vt, BATCH * S_LEN, 3 * DMODEL, DMODEL, 1);

    // attn (pure, verified 57.3us config)
    attn_kernel<<<dim3(BATCH * NH, S_LEN / 64), 512, 0, stream>>>(Qp, Kp, Vt, mask, ctx);

    // output projection: M=4096, N=1024, K=1024 -> fp32 out, 64x64 tiles, 512 threads
    gemm64<<<dim3(1024 / 64, 4096 / 64), 512, 0, stream>>>(
        ctx, Wproj_t, bproj, out, BATCH * S_LEN, DMODEL, DMODEL);
}